// Round 12
// baseline (181.741 us; speedup 1.0000x reference)
//
#include <hip/hip_runtime.h>

typedef __attribute__((ext_vector_type(8))) short short8;
typedef __attribute__((ext_vector_type(4))) float floatx4;

#define HW 4096
#define CIN 256
#define CK 128
#define COUT 256
#define NB 4
#define BN_EPS 1e-5f
// (1/sqrt(128)) * log2(e), folded into Q at projection time -> P = exp2(S)
#define SC2 0.12751744526f

#define MFMA(a, b, c) __builtin_amdgcn_mfma_f32_16x16x32_bf16((a), (b), (c), 0, 0, 0)

// f32 -> bf16, round-half-up (+0x8000). Differs from RNE only on exact ties;
// both are <=0.5 ulp from the fp32 value. 2 VALU ops.
__device__ __forceinline__ unsigned short f2bf(float f) {
  union { float f; unsigned u; } v; v.f = f;
  return (unsigned short)((v.u + 0x8000u) >> 16);
}

// pack {bf16(a) low, bf16(b) high} in 3 VALU ops: two rounding adds + one
// v_perm_b32 byte-select (D = [bu.3, bu.2, au.3, au.2] -> sel 0x07060302).
__device__ __forceinline__ unsigned pack2(float a, float b) {
  union { float f; unsigned u; } va, vb; va.f = a; vb.f = b;
  return __builtin_amdgcn_perm(vb.u + 0x8000u, va.u + 0x8000u, 0x07060302u);
}

__device__ __forceinline__ float bf2f(unsigned short u) {
  union { unsigned u; float f; } v; v.u = ((unsigned)u) << 16;
  return v.f;
}

__device__ __forceinline__ short8 pack8(const float* p) {
  union { unsigned u[4]; short8 s; } v;
  v.u[0] = pack2(p[0], p[1]);
  v.u[1] = pack2(p[2], p[3]);
  v.u[2] = pack2(p[4], p[5]);
  v.u[3] = pack2(p[6], p[7]);
  return v.s;
}

// Build one bf16 A-fragment (short8) from an fp32 weight row segment.
// Identical bytes to what prep_kernel used to produce (2xfloat4 + 4 pack2).
__device__ __forceinline__ short8 wfrag(const float* src) {
  const float4 a0 = *(const float4*)src;
  const float4 a1 = *(const float4*)(src + 4);
  union { unsigned u[4]; short8 s; } v;
  v.u[0] = pack2(a0.x, a0.y);
  v.u[1] = pack2(a0.z, a0.w);
  v.u[2] = pack2(a1.x, a1.y);
  v.u[3] = pack2(a1.z, a1.w);
  return v.s;
}

// ---------------------------------------------------------------------------
// Kernel 1: projections. grid (64, 4, 2), block 256. Structure known-good.
// THIS ROUND: prep_kernel deleted — W fragments are built inline from fp32
// (index-identical to the old packed arrays; W is L2-hot at 384 KB total).
// ---------------------------------------------------------------------------
__global__ __launch_bounds__(256) void proj_kernel(
    const float* __restrict__ x_enc, const float* __restrict__ x_dec,
    const float* __restrict__ wq, const float* __restrict__ wk,
    const float* __restrict__ wv,
    const float* __restrict__ bq, const float* __restrict__ gq,
    const float* __restrict__ betaq, const float* __restrict__ mq,
    const float* __restrict__ vq,
    const float* __restrict__ bk, const float* __restrict__ gk,
    const float* __restrict__ betak, const float* __restrict__ mk,
    const float* __restrict__ vk, const float* __restrict__ bv,
    unsigned short* __restrict__ Qb, unsigned short* __restrict__ Kb,
    unsigned short* __restrict__ Vt)
{
  const int tid = threadIdx.x;
  const int pt = blockIdx.x;
  const int b  = blockIdx.y;
  const int pj = blockIdx.z;

  const float* X = (pj == 0) ? x_dec : x_enc;

  __shared__ float xF[64 * 68];
  __shared__ unsigned short xT[64 * 264];

  const float* Xs = X + (size_t)b * CIN * HW + (size_t)pt * 64;
#pragma unroll
  for (int qtr = 0; qtr < 4; ++qtr) {
    if (qtr) __syncthreads();
    {
      const int c = tid >> 2;
      const int p0 = (tid & 3) * 16;
      const float* src = Xs + (size_t)(qtr * 64 + c) * HW + p0;
#pragma unroll
      for (int j = 0; j < 4; ++j)
        *(float4*)&xF[c * 68 + p0 + j * 4] = *(const float4*)(src + j * 4);
    }
    __syncthreads();
    {
      const int p = tid & 63;
      const int cb = tid >> 6;
#pragma unroll
      for (int jj = 0; jj < 2; ++jj) {
        const int c0 = (jj * 4 + cb) * 8;
        float t[8];
#pragma unroll
        for (int u = 0; u < 8; ++u) t[u] = xF[(c0 + u) * 68 + p];
        *(short8*)&xT[p * 264 + qtr * 64 + c0] = pack8(t);
      }
    }
  }
  __syncthreads();

  const int wave = tid >> 6;
  const int lane = tid & 63;
  const int lane16 = lane & 15;
  const int quad = lane >> 4;

  if (pj == 0) {
    floatx4 acc[2][4];
#pragma unroll
    for (int mt = 0; mt < 2; ++mt)
#pragma unroll
      for (int nf = 0; nf < 4; ++nf) acc[mt][nf] = (floatx4){0.f, 0.f, 0.f, 0.f};

#pragma unroll
    for (int ks = 0; ks < 8; ++ks) {
      short8 af[2];
#pragma unroll
      for (int mt = 0; mt < 2; ++mt) {
        const int o = wave * 32 + mt * 16 + lane16;
        af[mt] = wfrag(wq + (size_t)o * CIN + ks * 32 + quad * 8);
      }
#pragma unroll
      for (int nf = 0; nf < 4; ++nf) {
        const short8 bf = *(const short8*)&xT[(nf * 16 + lane16) * 264 + ks * 32 + quad * 8];
#pragma unroll
        for (int mt = 0; mt < 2; ++mt) acc[mt][nf] = MFMA(af[mt], bf, acc[mt][nf]);
      }
    }

    float sc[2][4], off[2][4];
#pragma unroll
    for (int mt = 0; mt < 2; ++mt)
#pragma unroll
      for (int r = 0; r < 4; ++r) {
        const int o = wave * 32 + mt * 16 + quad * 4 + r;
        const float s = gq[o] * rsqrtf(vq[o] + BN_EPS) * SC2;
        sc[mt][r] = s;
        off[mt][r] = (bq[o] - mq[o]) * s + betaq[o] * SC2;
      }
#pragma unroll
    for (int nf = 0; nf < 4; ++nf) {
      const size_t prow = ((size_t)b * HW + pt * 64 + nf * 16 + lane16) * CK;
#pragma unroll
      for (int mt = 0; mt < 2; ++mt) {
        const unsigned lo = pack2(fmaxf(acc[mt][nf][0] * sc[mt][0] + off[mt][0], 0.f),
                                  fmaxf(acc[mt][nf][1] * sc[mt][1] + off[mt][1], 0.f));
        const unsigned hi = pack2(fmaxf(acc[mt][nf][2] * sc[mt][2] + off[mt][2], 0.f),
                                  fmaxf(acc[mt][nf][3] * sc[mt][3] + off[mt][3], 0.f));
        *(uint2*)(Qb + prow + wave * 32 + mt * 16 + quad * 4) = make_uint2(lo, hi);
      }
    }
  } else {
    const bool isK = (wave < 2);
    floatx4 acc[4][4];
#pragma unroll
    for (int mt = 0; mt < 4; ++mt)
#pragma unroll
      for (int nf = 0; nf < 4; ++nf) acc[mt][nf] = (floatx4){0.f, 0.f, 0.f, 0.f};

#pragma unroll
    for (int ks = 0; ks < 8; ++ks) {
      short8 af[4];
#pragma unroll
      for (int mt = 0; mt < 4; ++mt) {
        const int o = wave * 64 + mt * 16 + lane16;  // waves 0-1: K (o<128), 2-3: V
        const float* row = isK ? (wk + (size_t)o * CIN)
                               : (wv + (size_t)(o - 128) * CIN);
        af[mt] = wfrag(row + ks * 32 + quad * 8);
      }
#pragma unroll
      for (int nf = 0; nf < 4; ++nf) {
        const short8 bf = *(const short8*)&xT[(nf * 16 + lane16) * 264 + ks * 32 + quad * 8];
#pragma unroll
        for (int mt = 0; mt < 4; ++mt) acc[mt][nf] = MFMA(af[mt], bf, acc[mt][nf]);
      }
    }

    if (isK) {
      float sc[4][4], off[4][4];
#pragma unroll
      for (int mt = 0; mt < 4; ++mt)
#pragma unroll
        for (int r = 0; r < 4; ++r) {
          const int o = wave * 64 + mt * 16 + quad * 4 + r;
          const float s = gk[o] * rsqrtf(vk[o] + BN_EPS);
          sc[mt][r] = s;
          off[mt][r] = (bk[o] - mk[o]) * s + betak[o];
        }
#pragma unroll
      for (int nf = 0; nf < 4; ++nf) {
        const size_t prow = ((size_t)b * HW + pt * 64 + nf * 16 + lane16) * CK;
#pragma unroll
        for (int mt = 0; mt < 4; ++mt) {
          const unsigned lo = pack2(fmaxf(acc[mt][nf][0] * sc[mt][0] + off[mt][0], 0.f),
                                    fmaxf(acc[mt][nf][1] * sc[mt][1] + off[mt][1], 0.f));
          const unsigned hi = pack2(fmaxf(acc[mt][nf][2] * sc[mt][2] + off[mt][2], 0.f),
                                    fmaxf(acc[mt][nf][3] * sc[mt][3] + off[mt][3], 0.f));
          *(uint2*)(Kb + prow + wave * 64 + mt * 16 + quad * 4) = make_uint2(lo, hi);
        }
      }
    } else {
#pragma unroll
      for (int mt = 0; mt < 4; ++mt) {
#pragma unroll
        for (int r = 0; r < 4; ++r) {
          const int c = wave * 64 + mt * 16 + quad * 4 + r - 128;
          const float bias = bv[c];
          unsigned short* dst = Vt + ((size_t)(b * CK + c)) * HW + pt * 64;
#pragma unroll
          for (int nf = 0; nf < 4; ++nf)
            dst[nf * 16 + lane16] = f2bf(acc[mt][nf][r] + bias);
        }
      }
    }
  }
}

// ---------------------------------------------------------------------------
// Kernel 2: split-K flash attention — 8-wave blocks, in-register P (sigma
// row permutation), double-buffered Kl/Vl, one barrier/iter, write-late
// staging, 3-op perm pack (round-11 structure, 44.6 us). THIS ROUND:
// wave-phase stagger — odd waves process kp in reverse order (O/Lacc
// accumulate both kp, so order is semantics-free). Breaks the 8-wave
// lockstep: half the waves issue QK^T MFMAs while the other half runs
// exp/pack/PV, overlapping the matrix and VALU pipes.
// grid 64*NKC (b=blk&3, qt=(blk>>2)&15, kc=blk>>6), block 512 (8 waves).
// ---------------------------------------------------------------------------
template<int NKC>
__global__ __launch_bounds__(512) void attn_kernel8(
    const unsigned short* __restrict__ Qb, const unsigned short* __restrict__ Kb,
    const unsigned short* __restrict__ Vt, unsigned short* __restrict__ OpartH,
    float* __restrict__ Ml)
{
  constexpr int ITERS = 64 / NKC;
  const int tid = threadIdx.x;
  const int blk = blockIdx.x;
  const int b  = blk & 3;
  const int qt = (blk >> 2) & 15;
  const int kc = blk >> 6;

  const int wave = tid >> 6;
  const int lane = tid & 63;
  const int lane16 = lane & 15;
  const int quad = lane >> 4;

  __shared__ unsigned short Kl[2][64 * 136];  // [buf][slot][c], stride 136
  __shared__ unsigned short Vl[2][128 * 72];  // [buf][c][kp], stride 72

  const int q0 = qt * 256 + wave * 32;
  short8 qf[2][4];
  {
    const unsigned short* Qs = Qb + ((size_t)b * HW + q0) * CK;
#pragma unroll
    for (int mt = 0; mt < 2; ++mt)
#pragma unroll
      for (int ks = 0; ks < 4; ++ks)
        qf[mt][ks] = *(const short8*)(Qs + (size_t)(mt * 16 + lane16) * CK + ks * 32 + quad * 8);
  }

  short8 ones;
#pragma unroll
  for (int i = 0; i < 8; ++i) ones[i] = (short)0x3F80;  // bf16 1.0

  floatx4 O[2][8];
  floatx4 Lacc[2];
#pragma unroll
  for (int mt = 0; mt < 2; ++mt) {
    Lacc[mt] = (floatx4){0.f, 0.f, 0.f, 0.f};
#pragma unroll
    for (int nf = 0; nf < 8; ++nf) O[mt][nf] = (floatx4){0.f, 0.f, 0.f, 0.f};
  }

  const int krow = tid >> 4;           // 0..31
  const int kcol = (tid & 15) * 8;     // shorts
  const int vrow = tid >> 2;           // 0..127 (channel)
  const int vcol = (tid & 3) * 16;     // shorts
  const int kpo  = wave & 1;           // per-wave kp phase offset (stagger)

  // staging slots for the 2 K rows this thread writes (g = krow + 32*i2)
  int kslot[2];
#pragma unroll
  for (int i2 = 0; i2 < 2; ++i2) {
    const int g = krow + i2 * 32;
    kslot[i2] = (g & 0x23) | ((g & 0x18) >> 1) | ((g & 0x04) << 2);
  }

  const unsigned short* Kg = Kb + ((size_t)b * HW + (size_t)kc * ITERS * 64) * CK;
  const unsigned short* Vg = Vt + (size_t)b * CK * HW + kc * ITERS * 64;

  short8 kr[2], vr[2];
#pragma unroll
  for (int i2 = 0; i2 < 2; ++i2)
    kr[i2] = *(const short8*)(Kg + (size_t)(krow + i2 * 32) * CK + kcol);
#pragma unroll
  for (int i2 = 0; i2 < 2; ++i2)
    vr[i2] = *(const short8*)(Vg + (size_t)vrow * HW + vcol + i2 * 8);

  // prologue: tile 0 into buffer 0
#pragma unroll
  for (int i2 = 0; i2 < 2; ++i2)
    *(short8*)&Kl[0][kslot[i2] * 136 + kcol] = kr[i2];
#pragma unroll
  for (int i2 = 0; i2 < 2; ++i2)
    *(short8*)&Vl[0][vrow * 72 + vcol + i2 * 8] = vr[i2];
  __syncthreads();

  for (int it = 0; it < ITERS; ++it) {
    const int cur = it & 1;
    const unsigned short* Klc = &Kl[cur][0];
    const unsigned short* Vlc = &Vl[cur][0];

    if (it + 1 < ITERS) {  // issue prefetch of tile t+1 (lands during compute)
      const unsigned short* Kn = Kg + (size_t)((it + 1) * 64) * CK;
      const unsigned short* Vn = Vg + (it + 1) * 64;
#pragma unroll
      for (int i2 = 0; i2 < 2; ++i2)
        kr[i2] = *(const short8*)(Kn + (size_t)(krow + i2 * 32) * CK + kcol);
#pragma unroll
      for (int i2 = 0; i2 < 2; ++i2)
        vr[i2] = *(const short8*)(Vn + (size_t)vrow * HW + vcol + i2 * 8);
    }

    __builtin_amdgcn_s_setprio(1);
    // Per 32-wide PV k-chunk: QK^T on tile pair (2kp, 2kp+1) -> exp2/pack
    // in-register -> PV straight from the packed A-frag. Odd waves take the
    // kp chunks in reverse order (accumulation is order-free).
#pragma unroll
    for (int kp2 = 0; kp2 < 2; ++kp2) {
      const int kp = kp2 ^ kpo;
      floatx4 sA0 = (floatx4){0.f, 0.f, 0.f, 0.f};
      floatx4 sA1 = (floatx4){0.f, 0.f, 0.f, 0.f};
      floatx4 sB0 = (floatx4){0.f, 0.f, 0.f, 0.f};
      floatx4 sB1 = (floatx4){0.f, 0.f, 0.f, 0.f};
#pragma unroll
      for (int ks = 0; ks < 4; ++ks) {
        const short8 kfA = *(const short8*)&Klc[((2 * kp) * 16 + lane16) * 136 + ks * 32 + quad * 8];
        const short8 kfB = *(const short8*)&Klc[((2 * kp + 1) * 16 + lane16) * 136 + ks * 32 + quad * 8];
        sA0 = MFMA(kfA, qf[0][ks], sA0);
        sA1 = MFMA(kfA, qf[1][ks], sA1);
        sB0 = MFMA(kfB, qf[0][ks], sB0);
        sB1 = MFMA(kfB, qf[1][ks], sB1);
      }
      union { unsigned u[4]; short8 s; } pf0, pf1;
      pf0.u[0] = pack2(__builtin_amdgcn_exp2f(sA0[0]), __builtin_amdgcn_exp2f(sA0[1]));
      pf0.u[1] = pack2(__builtin_amdgcn_exp2f(sA0[2]), __builtin_amdgcn_exp2f(sA0[3]));
      pf0.u[2] = pack2(__builtin_amdgcn_exp2f(sB0[0]), __builtin_amdgcn_exp2f(sB0[1]));
      pf0.u[3] = pack2(__builtin_amdgcn_exp2f(sB0[2]), __builtin_amdgcn_exp2f(sB0[3]));
      pf1.u[0] = pack2(__builtin_amdgcn_exp2f(sA1[0]), __builtin_amdgcn_exp2f(sA1[1]));
      pf1.u[1] = pack2(__builtin_amdgcn_exp2f(sA1[2]), __builtin_amdgcn_exp2f(sA1[3]));
      pf1.u[2] = pack2(__builtin_amdgcn_exp2f(sB1[0]), __builtin_amdgcn_exp2f(sB1[1]));
      pf1.u[3] = pack2(__builtin_amdgcn_exp2f(sB1[2]), __builtin_amdgcn_exp2f(sB1[3]));

      Lacc[0] = MFMA(pf0.s, ones, Lacc[0]);
      Lacc[1] = MFMA(pf1.s, ones, Lacc[1]);
#pragma unroll
      for (int nf = 0; nf < 8; ++nf) {
        const short8 vf = *(const short8*)&Vlc[(nf * 16 + lane16) * 72 + kp * 32 + quad * 8];
        O[0][nf] = MFMA(pf0.s, vf, O[0][nf]);
        O[1][nf] = MFMA(pf1.s, vf, O[1][nf]);
      }
    }
    __builtin_amdgcn_s_setprio(0);

    if (it + 1 < ITERS) {  // write-late: stage tile t+1 into the other buffer
      const int nxt = cur ^ 1;
#pragma unroll
      for (int i2 = 0; i2 < 2; ++i2)
        *(short8*)&Kl[nxt][kslot[i2] * 136 + kcol] = kr[i2];
#pragma unroll
      for (int i2 = 0; i2 < 2; ++i2)
        *(short8*)&Vl[nxt][vrow * 72 + vcol + i2 * 8] = vr[i2];
    }
    __syncthreads();
  }

  // epilogue: bf16 unnormalized partial O + fp32 l. Waves 0-3 -> even
  // 128-row chunk (qt*2), waves 4-7 -> odd chunk (qt*2+1); row uses wave&3.
  const int qt128 = qt * 2 + (wave >> 2);
  const int w4 = wave & 3;
  const int chunk = (b * 32 + qt128) * NKC + kc;
  unsigned short* Op = OpartH + (size_t)chunk * (128 * 128);
#pragma unroll
  for (int mt = 0; mt < 2; ++mt)
#pragma unroll
    for (int nf = 0; nf < 8; ++nf)
#pragma unroll
      for (int r = 0; r < 4; ++r)
        Op[(size_t)(w4 * 32 + mt * 16 + quad * 4 + r) * 128 + nf * 16 + lane16] =
            f2bf(O[mt][nf][r]);
  if (lane16 == 0) {
    float* Mp = Ml + (size_t)chunk * 128 + w4 * 32;
#pragma unroll
    for (int mt = 0; mt < 2; ++mt)
#pragma unroll
      for (int r = 0; r < 4; ++r)
        Mp[mt * 16 + quad * 4 + r] = Lacc[mt][r];
  }
}

// ---------------------------------------------------------------------------
// Kernel 3: fused combine + out-projection. Wo fragments built inline from
// fp32 (prep deleted). grid (256 p-tiles of 16, 4 batch), block 256.
// ---------------------------------------------------------------------------
template<int NKC>
__global__ __launch_bounds__(256) void outproj_kernel(
    const unsigned short* __restrict__ OpartH, const float* __restrict__ Ml,
    const float* __restrict__ wo, const float* __restrict__ bo,
    float* __restrict__ out)
{
  const int tid = threadIdx.x;
  const int pt = blockIdx.x;
  const int b  = blockIdx.y;
  const int qt = pt >> 3;
  const int q0 = (pt & 7) * 16;
  const int chunk0 = (b * 32 + qt) * NKC;

  __shared__ unsigned short Ctile[16 * 136];

  {
    const int row = tid >> 4;
    const int c8  = (tid & 15) * 8;
    float L = 0.f;
#pragma unroll
    for (int k = 0; k < NKC; ++k) L += Ml[(size_t)(chunk0 + k) * 128 + q0 + row];
    float acc[8];
#pragma unroll
    for (int i = 0; i < 8; ++i) acc[i] = 0.f;
#pragma unroll
    for (int k = 0; k < NKC; ++k) {
      const short8 v = *(const short8*)(OpartH + (size_t)(chunk0 + k) * 16384 +
                                        (size_t)(q0 + row) * 128 + c8);
#pragma unroll
      for (int i = 0; i < 8; ++i) acc[i] += bf2f((unsigned short)v[i]);
    }
    const float inv = 1.f / L;
#pragma unroll
    for (int i = 0; i < 8; ++i) acc[i] *= inv;
    *(short8*)&Ctile[row * 136 + c8] = pack8(acc);
  }
  __syncthreads();

  const int wave = tid >> 6;
  const int lane = tid & 63;
  const int lane16 = lane & 15;
  const int quad = lane >> 4;

  floatx4 acc[4];
#pragma unroll
  for (int mt = 0; mt < 4; ++mt) acc[mt] = (floatx4){0.f, 0.f, 0.f, 0.f};

#pragma unroll
  for (int ks = 0; ks < 4; ++ks) {
    const short8 bf = *(const short8*)&Ctile[lane16 * 136 + ks * 32 + quad * 8];
#pragma unroll
    for (int mt = 0; mt < 4; ++mt) {
      const int o = wave * 64 + mt * 16 + lane16;
      const short8 af = wfrag(wo + (size_t)o * CK + ks * 32 + quad * 8);
      acc[mt] = MFMA(af, bf, acc[mt]);
    }
  }

#pragma unroll
  for (int mt = 0; mt < 4; ++mt) {
#pragma unroll
    for (int r = 0; r < 4; ++r) {
      const int o = wave * 64 + mt * 16 + quad * 4 + r;
      float* dst = out + ((size_t)b * COUT + o) * HW + qt * 128 + q0;
      dst[lane16] = acc[mt][r] + bo[o];
    }
  }
}

extern "C" void kernel_launch(void* const* d_in, const int* in_sizes, int n_in,
                              void* d_out, int out_size, void* d_ws, size_t ws_size,
                              hipStream_t stream)
{
  (void)in_sizes; (void)n_in; (void)out_size;
  const float* x_enc = (const float*)d_in[0];
  const float* x_dec = (const float*)d_in[1];
  const float* wk    = (const float*)d_in[2];
  const float* bk    = (const float*)d_in[3];
  const float* gk    = (const float*)d_in[4];
  const float* betak = (const float*)d_in[5];
  const float* mk    = (const float*)d_in[6];
  const float* vk    = (const float*)d_in[7];
  const float* wq    = (const float*)d_in[8];
  const float* bq    = (const float*)d_in[9];
  const float* gq    = (const float*)d_in[10];
  const float* betaq = (const float*)d_in[11];
  const float* mq    = (const float*)d_in[12];
  const float* vq    = (const float*)d_in[13];
  const float* wv    = (const float*)d_in[14];
  const float* bv    = (const float*)d_in[15];
  const float* wo    = (const float*)d_in[16];
  const float* bo    = (const float*)d_in[17];
  float* out = (float*)d_out;

  const size_t qkv = (size_t)NB * HW * CK;  // elems per bf16 tensor
  unsigned short* Qb   = (unsigned short*)d_ws;
  unsigned short* Kb   = Qb + qkv;
  unsigned short* Vt   = Kb + qkv;
  unsigned short* OpartH = Vt + qkv;                 // bf16 partials
  const size_t fixed_bytes = 3 * qkv * 2;

  proj_kernel<<<dim3(64, 4, 2), 256, 0, stream>>>(
      x_enc, x_dec, wq, wk, wv,
      bq, gq, betaq, mq, vq, bk, gk, betak, mk, vk, bv, Qb, Kb, Vt);

  auto need = [&](int nkc) {
    return fixed_bytes + (size_t)128 * nkc * 16384 * 2      // OpartH bf16
                       + (size_t)128 * nkc * 128 * 4;       // Ml fp32
  };
  if (ws_size >= need(8)) {
    float* Ml = (float*)(OpartH + (size_t)128 * 8 * 16384);
    attn_kernel8<8><<<dim3(512), 512, 0, stream>>>(Qb, Kb, Vt, OpartH, Ml);
    outproj_kernel<8><<<dim3(256, 4), 256, 0, stream>>>(OpartH, Ml, wo, bo, out);
  } else if (ws_size >= need(4)) {
    float* Ml = (float*)(OpartH + (size_t)128 * 4 * 16384);
    attn_kernel8<4><<<dim3(256), 512, 0, stream>>>(Qb, Kb, Vt, OpartH, Ml);
    outproj_kernel<4><<<dim3(256, 4), 256, 0, stream>>>(OpartH, Ml, wo, bo, out);
  } else if (ws_size >= need(2)) {
    float* Ml = (float*)(OpartH + (size_t)128 * 2 * 16384);
    attn_kernel8<2><<<dim3(128), 512, 0, stream>>>(Qb, Kb, Vt, OpartH, Ml);
    outproj_kernel<2><<<dim3(256, 4), 256, 0, stream>>>(OpartH, Ml, wo, bo, out);
  } else {
    float* Ml = (float*)(OpartH + (size_t)128 * 1 * 16384);
    attn_kernel8<1><<<dim3(64), 512, 0, stream>>>(Qb, Kb, Vt, OpartH, Ml);
    outproj_kernel<1><<<dim3(256, 4), 256, 0, stream>>>(OpartH, Ml, wo, bo, out);
  }
}

// Round 13
// 171.281 us; speedup vs baseline: 1.0611x; 1.0611x over previous
//
#include <hip/hip_runtime.h>

typedef __attribute__((ext_vector_type(8))) short short8;
typedef __attribute__((ext_vector_type(4))) float floatx4;

#define HW 4096
#define CIN 256
#define CK 128
#define COUT 256
#define NB 4
#define BN_EPS 1e-5f
// (1/sqrt(128)) * log2(e), folded into Q at projection time -> P = exp2(S)
#define SC2 0.12751744526f

#define MFMA(a, b, c) __builtin_amdgcn_mfma_f32_16x16x32_bf16((a), (b), (c), 0, 0, 0)

// f32 -> bf16, round-half-up (+0x8000). Differs from RNE only on exact ties;
// both are <=0.5 ulp from the fp32 value. 2 VALU ops.
__device__ __forceinline__ unsigned short f2bf(float f) {
  union { float f; unsigned u; } v; v.f = f;
  return (unsigned short)((v.u + 0x8000u) >> 16);
}

// pack {bf16(a) low, bf16(b) high} in 3 VALU ops: two rounding adds + one
// v_perm_b32 byte-select (D = [bu.3, bu.2, au.3, au.2] -> sel 0x07060302).
__device__ __forceinline__ unsigned pack2(float a, float b) {
  union { float f; unsigned u; } va, vb; va.f = a; vb.f = b;
  return __builtin_amdgcn_perm(vb.u + 0x8000u, va.u + 0x8000u, 0x07060302u);
}

__device__ __forceinline__ float bf2f(unsigned short u) {
  union { unsigned u; float f; } v; v.u = ((unsigned)u) << 16;
  return v.f;
}

__device__ __forceinline__ short8 pack8(const float* p) {
  union { unsigned u[4]; short8 s; } v;
  v.u[0] = pack2(p[0], p[1]);
  v.u[1] = pack2(p[2], p[3]);
  v.u[2] = pack2(p[4], p[5]);
  v.u[3] = pack2(p[6], p[7]);
  return v.s;
}

// ---------------------------------------------------------------------------
// Kernel 0: pre-pack weights as bf16 in MFMA A-fragment order (coalesced
// 16B/lane loads in proj/outproj). (RESTORED — r12's inline-W cost ~12 us.)
// ---------------------------------------------------------------------------
__global__ __launch_bounds__(256) void prep_kernel(
    const float* __restrict__ wq, const float* __restrict__ wk,
    const float* __restrict__ wv, const float* __restrict__ wo,
    unsigned short* __restrict__ WqP, unsigned short* __restrict__ WkvP,
    unsigned short* __restrict__ WoP)
{
  const int t = blockIdx.x * 256 + threadIdx.x;  // 0..16383
  float tmp[8];
  if (t < 4096) {
    const int lane = t & 63, mt = (t >> 6) & 1, wave = (t >> 7) & 3, ks = t >> 9;
    const int lane16 = lane & 15, quad = lane >> 4;
    const int o = wave * 32 + mt * 16 + lane16;
    const float* src = wq + (size_t)o * CIN + ks * 32 + quad * 8;
    *(float4*)tmp = *(const float4*)src;
    *(float4*)(tmp + 4) = *(const float4*)(src + 4);
    *(short8*)&WqP[(size_t)t * 8] = pack8(tmp);
  } else if (t < 12288) {
    const int u = t - 4096;
    const int lane = u & 63, mt = (u >> 6) & 3, wave = (u >> 8) & 3, ks = u >> 10;
    const int lane16 = lane & 15, quad = lane >> 4;
    const int o = wave * 64 + mt * 16 + lane16;
    const float* row = (o < 128) ? wk + (size_t)o * CIN : wv + (size_t)(o - 128) * CIN;
    const float* src = row + ks * 32 + quad * 8;
    *(float4*)tmp = *(const float4*)src;
    *(float4*)(tmp + 4) = *(const float4*)(src + 4);
    *(short8*)&WkvP[(size_t)u * 8] = pack8(tmp);
  } else {
    const int u = t - 12288;
    const int lane = u & 63, mt = (u >> 6) & 3, wave = (u >> 8) & 3, ks = u >> 10;
    const int lane16 = lane & 15, quad = lane >> 4;
    const int o = wave * 64 + mt * 16 + lane16;
    const float* src = wo + (size_t)o * CK + ks * 32 + quad * 8;
    *(float4*)tmp = *(const float4*)src;
    *(float4*)(tmp + 4) = *(const float4*)(src + 4);
    *(short8*)&WoP[(size_t)u * 8] = pack8(tmp);
  }
}

// ---------------------------------------------------------------------------
// Kernel 1: projections. grid (64, 4, 2), block 256. Round-11 structure
// (packed weights) + THIS ROUND: qtr-prefetch — the next qtr's 4 float4
// global loads are issued right after the staging-visible barrier, so their
// ~500cy latency hides under the transpose phase (T14; r2-proven in attn).
// ---------------------------------------------------------------------------
__global__ __launch_bounds__(256) void proj_kernel(
    const float* __restrict__ x_enc, const float* __restrict__ x_dec,
    const unsigned short* __restrict__ WqP, const unsigned short* __restrict__ WkvP,
    const float* __restrict__ bq, const float* __restrict__ gq,
    const float* __restrict__ betaq, const float* __restrict__ mq,
    const float* __restrict__ vq,
    const float* __restrict__ bk, const float* __restrict__ gk,
    const float* __restrict__ betak, const float* __restrict__ mk,
    const float* __restrict__ vk, const float* __restrict__ bv,
    unsigned short* __restrict__ Qb, unsigned short* __restrict__ Kb,
    unsigned short* __restrict__ Vt)
{
  const int tid = threadIdx.x;
  const int pt = blockIdx.x;
  const int b  = blockIdx.y;
  const int pj = blockIdx.z;

  const float* X = (pj == 0) ? x_dec : x_enc;

  __shared__ float xF[64 * 68];
  __shared__ unsigned short xT[64 * 264];

  const float* Xs = X + (size_t)b * CIN * HW + (size_t)pt * 64;
  const int c  = tid >> 2;
  const int p0 = (tid & 3) * 16;

  float4 pre[4];
  {
    const float* src = Xs + (size_t)c * HW + p0;
#pragma unroll
    for (int j = 0; j < 4; ++j) pre[j] = *(const float4*)(src + j * 4);
  }
#pragma unroll
  for (int qtr = 0; qtr < 4; ++qtr) {
    if (qtr) __syncthreads();   // previous transpose reads of xF complete
#pragma unroll
    for (int j = 0; j < 4; ++j)
      *(float4*)&xF[c * 68 + p0 + j * 4] = pre[j];
    __syncthreads();            // staging visible
    if (qtr < 3) {              // prefetch next qtr (overlaps transpose below)
      const float* src = Xs + (size_t)((qtr + 1) * 64 + c) * HW + p0;
#pragma unroll
      for (int j = 0; j < 4; ++j) pre[j] = *(const float4*)(src + j * 4);
    }
    {
      const int p = tid & 63;
      const int cb = tid >> 6;
#pragma unroll
      for (int jj = 0; jj < 2; ++jj) {
        const int c0 = (jj * 4 + cb) * 8;
        float t[8];
#pragma unroll
        for (int u = 0; u < 8; ++u) t[u] = xF[(c0 + u) * 68 + p];
        *(short8*)&xT[p * 264 + qtr * 64 + c0] = pack8(t);
      }
    }
  }
  __syncthreads();

  const int wave = tid >> 6;
  const int lane = tid & 63;
  const int lane16 = lane & 15;
  const int quad = lane >> 4;

  if (pj == 0) {
    floatx4 acc[2][4];
#pragma unroll
    for (int mt = 0; mt < 2; ++mt)
#pragma unroll
      for (int nf = 0; nf < 4; ++nf) acc[mt][nf] = (floatx4){0.f, 0.f, 0.f, 0.f};

#pragma unroll
    for (int ks = 0; ks < 8; ++ks) {
      short8 af[2];
#pragma unroll
      for (int mt = 0; mt < 2; ++mt)
        af[mt] = *(const short8*)&WqP[(size_t)((((ks * 4 + wave) * 2 + mt) * 64) + lane) * 8];
#pragma unroll
      for (int nf = 0; nf < 4; ++nf) {
        const short8 bf = *(const short8*)&xT[(nf * 16 + lane16) * 264 + ks * 32 + quad * 8];
#pragma unroll
        for (int mt = 0; mt < 2; ++mt) acc[mt][nf] = MFMA(af[mt], bf, acc[mt][nf]);
      }
    }

    float sc[2][4], off[2][4];
#pragma unroll
    for (int mt = 0; mt < 2; ++mt)
#pragma unroll
      for (int r = 0; r < 4; ++r) {
        const int o = wave * 32 + mt * 16 + quad * 4 + r;
        const float s = gq[o] * rsqrtf(vq[o] + BN_EPS) * SC2;
        sc[mt][r] = s;
        off[mt][r] = (bq[o] - mq[o]) * s + betaq[o] * SC2;
      }
#pragma unroll
    for (int nf = 0; nf < 4; ++nf) {
      const size_t prow = ((size_t)b * HW + pt * 64 + nf * 16 + lane16) * CK;
#pragma unroll
      for (int mt = 0; mt < 2; ++mt) {
        const unsigned lo = pack2(fmaxf(acc[mt][nf][0] * sc[mt][0] + off[mt][0], 0.f),
                                  fmaxf(acc[mt][nf][1] * sc[mt][1] + off[mt][1], 0.f));
        const unsigned hi = pack2(fmaxf(acc[mt][nf][2] * sc[mt][2] + off[mt][2], 0.f),
                                  fmaxf(acc[mt][nf][3] * sc[mt][3] + off[mt][3], 0.f));
        *(uint2*)(Qb + prow + wave * 32 + mt * 16 + quad * 4) = make_uint2(lo, hi);
      }
    }
  } else {
    const bool isK = (wave < 2);
    floatx4 acc[4][4];
#pragma unroll
    for (int mt = 0; mt < 4; ++mt)
#pragma unroll
      for (int nf = 0; nf < 4; ++nf) acc[mt][nf] = (floatx4){0.f, 0.f, 0.f, 0.f};

#pragma unroll
    for (int ks = 0; ks < 8; ++ks) {
      short8 af[4];
#pragma unroll
      for (int mt = 0; mt < 4; ++mt)
        af[mt] = *(const short8*)&WkvP[(size_t)((((ks * 4 + wave) * 4 + mt) * 64) + lane) * 8];
#pragma unroll
      for (int nf = 0; nf < 4; ++nf) {
        const short8 bf = *(const short8*)&xT[(nf * 16 + lane16) * 264 + ks * 32 + quad * 8];
#pragma unroll
        for (int mt = 0; mt < 4; ++mt) acc[mt][nf] = MFMA(af[mt], bf, acc[mt][nf]);
      }
    }

    if (isK) {
      float sc[4][4], off[4][4];
#pragma unroll
      for (int mt = 0; mt < 4; ++mt)
#pragma unroll
        for (int r = 0; r < 4; ++r) {
          const int o = wave * 64 + mt * 16 + quad * 4 + r;
          const float s = gk[o] * rsqrtf(vk[o] + BN_EPS);
          sc[mt][r] = s;
          off[mt][r] = (bk[o] - mk[o]) * s + betak[o];
        }
#pragma unroll
      for (int nf = 0; nf < 4; ++nf) {
        const size_t prow = ((size_t)b * HW + pt * 64 + nf * 16 + lane16) * CK;
#pragma unroll
        for (int mt = 0; mt < 4; ++mt) {
          const unsigned lo = pack2(fmaxf(acc[mt][nf][0] * sc[mt][0] + off[mt][0], 0.f),
                                    fmaxf(acc[mt][nf][1] * sc[mt][1] + off[mt][1], 0.f));
          const unsigned hi = pack2(fmaxf(acc[mt][nf][2] * sc[mt][2] + off[mt][2], 0.f),
                                    fmaxf(acc[mt][nf][3] * sc[mt][3] + off[mt][3], 0.f));
          *(uint2*)(Kb + prow + wave * 64 + mt * 16 + quad * 4) = make_uint2(lo, hi);
        }
      }
    } else {
#pragma unroll
      for (int mt = 0; mt < 4; ++mt) {
#pragma unroll
        for (int r = 0; r < 4; ++r) {
          const int c2 = wave * 64 + mt * 16 + quad * 4 + r - 128;
          const float bias = bv[c2];
          unsigned short* dst = Vt + ((size_t)(b * CK + c2)) * HW + pt * 64;
#pragma unroll
          for (int nf = 0; nf < 4; ++nf)
            dst[nf * 16 + lane16] = f2bf(acc[mt][nf][r] + bias);
        }
      }
    }
  }
}

// ---------------------------------------------------------------------------
// Kernel 2: split-K flash attention — EXACT round-11 code (44.6 us): 8-wave
// blocks, in-register P (sigma row permutation), double-buffered Kl/Vl, one
// barrier/iter, write-late staging, 3-op perm pack, NO stagger (r12's
// runtime-kp stagger regressed 5 us by defeating static scheduling).
// grid 64*NKC (b=blk&3, qt=(blk>>2)&15, kc=blk>>6), block 512 (8 waves).
// ---------------------------------------------------------------------------
template<int NKC>
__global__ __launch_bounds__(512) void attn_kernel8(
    const unsigned short* __restrict__ Qb, const unsigned short* __restrict__ Kb,
    const unsigned short* __restrict__ Vt, unsigned short* __restrict__ OpartH,
    float* __restrict__ Ml)
{
  constexpr int ITERS = 64 / NKC;
  const int tid = threadIdx.x;
  const int blk = blockIdx.x;
  const int b  = blk & 3;
  const int qt = (blk >> 2) & 15;
  const int kc = blk >> 6;

  const int wave = tid >> 6;
  const int lane = tid & 63;
  const int lane16 = lane & 15;
  const int quad = lane >> 4;

  __shared__ unsigned short Kl[2][64 * 136];  // [buf][slot][c], stride 136
  __shared__ unsigned short Vl[2][128 * 72];  // [buf][c][kp], stride 72

  const int q0 = qt * 256 + wave * 32;
  short8 qf[2][4];
  {
    const unsigned short* Qs = Qb + ((size_t)b * HW + q0) * CK;
#pragma unroll
    for (int mt = 0; mt < 2; ++mt)
#pragma unroll
      for (int ks = 0; ks < 4; ++ks)
        qf[mt][ks] = *(const short8*)(Qs + (size_t)(mt * 16 + lane16) * CK + ks * 32 + quad * 8);
  }

  short8 ones;
#pragma unroll
  for (int i = 0; i < 8; ++i) ones[i] = (short)0x3F80;  // bf16 1.0

  floatx4 O[2][8];
  floatx4 Lacc[2];
#pragma unroll
  for (int mt = 0; mt < 2; ++mt) {
    Lacc[mt] = (floatx4){0.f, 0.f, 0.f, 0.f};
#pragma unroll
    for (int nf = 0; nf < 8; ++nf) O[mt][nf] = (floatx4){0.f, 0.f, 0.f, 0.f};
  }

  const int krow = tid >> 4;           // 0..31
  const int kcol = (tid & 15) * 8;     // shorts
  const int vrow = tid >> 2;           // 0..127 (channel)
  const int vcol = (tid & 3) * 16;     // shorts

  // staging slots for the 2 K rows this thread writes (g = krow + 32*i2)
  int kslot[2];
#pragma unroll
  for (int i2 = 0; i2 < 2; ++i2) {
    const int g = krow + i2 * 32;
    kslot[i2] = (g & 0x23) | ((g & 0x18) >> 1) | ((g & 0x04) << 2);
  }

  const unsigned short* Kg = Kb + ((size_t)b * HW + (size_t)kc * ITERS * 64) * CK;
  const unsigned short* Vg = Vt + (size_t)b * CK * HW + kc * ITERS * 64;

  short8 kr[2], vr[2];
#pragma unroll
  for (int i2 = 0; i2 < 2; ++i2)
    kr[i2] = *(const short8*)(Kg + (size_t)(krow + i2 * 32) * CK + kcol);
#pragma unroll
  for (int i2 = 0; i2 < 2; ++i2)
    vr[i2] = *(const short8*)(Vg + (size_t)vrow * HW + vcol + i2 * 8);

  // prologue: tile 0 into buffer 0
#pragma unroll
  for (int i2 = 0; i2 < 2; ++i2)
    *(short8*)&Kl[0][kslot[i2] * 136 + kcol] = kr[i2];
#pragma unroll
  for (int i2 = 0; i2 < 2; ++i2)
    *(short8*)&Vl[0][vrow * 72 + vcol + i2 * 8] = vr[i2];
  __syncthreads();

  for (int it = 0; it < ITERS; ++it) {
    const int cur = it & 1;
    const unsigned short* Klc = &Kl[cur][0];
    const unsigned short* Vlc = &Vl[cur][0];

    if (it + 1 < ITERS) {  // issue prefetch of tile t+1 (lands during compute)
      const unsigned short* Kn = Kg + (size_t)((it + 1) * 64) * CK;
      const unsigned short* Vn = Vg + (it + 1) * 64;
#pragma unroll
      for (int i2 = 0; i2 < 2; ++i2)
        kr[i2] = *(const short8*)(Kn + (size_t)(krow + i2 * 32) * CK + kcol);
#pragma unroll
      for (int i2 = 0; i2 < 2; ++i2)
        vr[i2] = *(const short8*)(Vn + (size_t)vrow * HW + vcol + i2 * 8);
    }

    __builtin_amdgcn_s_setprio(1);
    // Per 32-wide PV k-chunk: QK^T on tile pair (2kp, 2kp+1) -> exp2/pack
    // in-register -> PV straight from the packed A-frag. No LDS for P.
#pragma unroll
    for (int kp = 0; kp < 2; ++kp) {
      floatx4 sA0 = (floatx4){0.f, 0.f, 0.f, 0.f};
      floatx4 sA1 = (floatx4){0.f, 0.f, 0.f, 0.f};
      floatx4 sB0 = (floatx4){0.f, 0.f, 0.f, 0.f};
      floatx4 sB1 = (floatx4){0.f, 0.f, 0.f, 0.f};
#pragma unroll
      for (int ks = 0; ks < 4; ++ks) {
        const short8 kfA = *(const short8*)&Klc[((2 * kp) * 16 + lane16) * 136 + ks * 32 + quad * 8];
        const short8 kfB = *(const short8*)&Klc[((2 * kp + 1) * 16 + lane16) * 136 + ks * 32 + quad * 8];
        sA0 = MFMA(kfA, qf[0][ks], sA0);
        sA1 = MFMA(kfA, qf[1][ks], sA1);
        sB0 = MFMA(kfB, qf[0][ks], sB0);
        sB1 = MFMA(kfB, qf[1][ks], sB1);
      }
      union { unsigned u[4]; short8 s; } pf0, pf1;
      pf0.u[0] = pack2(__builtin_amdgcn_exp2f(sA0[0]), __builtin_amdgcn_exp2f(sA0[1]));
      pf0.u[1] = pack2(__builtin_amdgcn_exp2f(sA0[2]), __builtin_amdgcn_exp2f(sA0[3]));
      pf0.u[2] = pack2(__builtin_amdgcn_exp2f(sB0[0]), __builtin_amdgcn_exp2f(sB0[1]));
      pf0.u[3] = pack2(__builtin_amdgcn_exp2f(sB0[2]), __builtin_amdgcn_exp2f(sB0[3]));
      pf1.u[0] = pack2(__builtin_amdgcn_exp2f(sA1[0]), __builtin_amdgcn_exp2f(sA1[1]));
      pf1.u[1] = pack2(__builtin_amdgcn_exp2f(sA1[2]), __builtin_amdgcn_exp2f(sA1[3]));
      pf1.u[2] = pack2(__builtin_amdgcn_exp2f(sB1[0]), __builtin_amdgcn_exp2f(sB1[1]));
      pf1.u[3] = pack2(__builtin_amdgcn_exp2f(sB1[2]), __builtin_amdgcn_exp2f(sB1[3]));

      Lacc[0] = MFMA(pf0.s, ones, Lacc[0]);
      Lacc[1] = MFMA(pf1.s, ones, Lacc[1]);
#pragma unroll
      for (int nf = 0; nf < 8; ++nf) {
        const short8 vf = *(const short8*)&Vlc[(nf * 16 + lane16) * 72 + kp * 32 + quad * 8];
        O[0][nf] = MFMA(pf0.s, vf, O[0][nf]);
        O[1][nf] = MFMA(pf1.s, vf, O[1][nf]);
      }
    }
    __builtin_amdgcn_s_setprio(0);

    if (it + 1 < ITERS) {  // write-late: stage tile t+1 into the other buffer
      const int nxt = cur ^ 1;
#pragma unroll
      for (int i2 = 0; i2 < 2; ++i2)
        *(short8*)&Kl[nxt][kslot[i2] * 136 + kcol] = kr[i2];
#pragma unroll
      for (int i2 = 0; i2 < 2; ++i2)
        *(short8*)&Vl[nxt][vrow * 72 + vcol + i2 * 8] = vr[i2];
    }
    __syncthreads();
  }

  // epilogue: bf16 unnormalized partial O + fp32 l. Waves 0-3 -> even
  // 128-row chunk (qt*2), waves 4-7 -> odd chunk (qt*2+1); row uses wave&3.
  const int qt128 = qt * 2 + (wave >> 2);
  const int w4 = wave & 3;
  const int chunk = (b * 32 + qt128) * NKC + kc;
  unsigned short* Op = OpartH + (size_t)chunk * (128 * 128);
#pragma unroll
  for (int mt = 0; mt < 2; ++mt)
#pragma unroll
    for (int nf = 0; nf < 8; ++nf)
#pragma unroll
      for (int r = 0; r < 4; ++r)
        Op[(size_t)(w4 * 32 + mt * 16 + quad * 4 + r) * 128 + nf * 16 + lane16] =
            f2bf(O[mt][nf][r]);
  if (lane16 == 0) {
    float* Mp = Ml + (size_t)chunk * 128 + w4 * 32;
#pragma unroll
    for (int mt = 0; mt < 2; ++mt)
#pragma unroll
      for (int r = 0; r < 4; ++r)
        Mp[mt * 16 + quad * 4 + r] = Lacc[mt][r];
  }
}

// ---------------------------------------------------------------------------
// Kernel 3: fused combine + out-projection (bf16 partials, packed WoP).
// grid (256 p-tiles of 16, 4 batch), block 256. (round-11 code)
// ---------------------------------------------------------------------------
template<int NKC>
__global__ __launch_bounds__(256) void outproj_kernel(
    const unsigned short* __restrict__ OpartH, const float* __restrict__ Ml,
    const unsigned short* __restrict__ WoP, const float* __restrict__ bo,
    float* __restrict__ out)
{
  const int tid = threadIdx.x;
  const int pt = blockIdx.x;
  const int b  = blockIdx.y;
  const int qt = pt >> 3;
  const int q0 = (pt & 7) * 16;
  const int chunk0 = (b * 32 + qt) * NKC;

  __shared__ unsigned short Ctile[16 * 136];

  {
    const int row = tid >> 4;
    const int c8  = (tid & 15) * 8;
    float L = 0.f;
#pragma unroll
    for (int k = 0; k < NKC; ++k) L += Ml[(size_t)(chunk0 + k) * 128 + q0 + row];
    float acc[8];
#pragma unroll
    for (int i = 0; i < 8; ++i) acc[i] = 0.f;
#pragma unroll
    for (int k = 0; k < NKC; ++k) {
      const short8 v = *(const short8*)(OpartH + (size_t)(chunk0 + k) * 16384 +
                                        (size_t)(q0 + row) * 128 + c8);
#pragma unroll
      for (int i = 0; i < 8; ++i) acc[i] += bf2f((unsigned short)v[i]);
    }
    const float inv = 1.f / L;
#pragma unroll
    for (int i = 0; i < 8; ++i) acc[i] *= inv;
    *(short8*)&Ctile[row * 136 + c8] = pack8(acc);
  }
  __syncthreads();

  const int wave = tid >> 6;
  const int lane = tid & 63;
  const int lane16 = lane & 15;
  const int quad = lane >> 4;

  floatx4 acc[4];
#pragma unroll
  for (int mt = 0; mt < 4; ++mt) acc[mt] = (floatx4){0.f, 0.f, 0.f, 0.f};

#pragma unroll
  for (int ks = 0; ks < 4; ++ks) {
    const short8 bf = *(const short8*)&Ctile[lane16 * 136 + ks * 32 + quad * 8];
#pragma unroll
    for (int mt = 0; mt < 4; ++mt) {
      const short8 af = *(const short8*)&WoP[(size_t)((((ks * 4 + wave) * 4 + mt) * 64) + lane) * 8];
      acc[mt] = MFMA(af, bf, acc[mt]);
    }
  }

#pragma unroll
  for (int mt = 0; mt < 4; ++mt) {
#pragma unroll
    for (int r = 0; r < 4; ++r) {
      const int o = wave * 64 + mt * 16 + quad * 4 + r;
      float* dst = out + ((size_t)b * COUT + o) * HW + qt * 128 + q0;
      dst[lane16] = acc[mt][r] + bo[o];
    }
  }
}

extern "C" void kernel_launch(void* const* d_in, const int* in_sizes, int n_in,
                              void* d_out, int out_size, void* d_ws, size_t ws_size,
                              hipStream_t stream)
{
  (void)in_sizes; (void)n_in; (void)out_size;
  const float* x_enc = (const float*)d_in[0];
  const float* x_dec = (const float*)d_in[1];
  const float* wk    = (const float*)d_in[2];
  const float* bk    = (const float*)d_in[3];
  const float* gk    = (const float*)d_in[4];
  const float* betak = (const float*)d_in[5];
  const float* mk    = (const float*)d_in[6];
  const float* vk    = (const float*)d_in[7];
  const float* wq    = (const float*)d_in[8];
  const float* bq    = (const float*)d_in[9];
  const float* gq    = (const float*)d_in[10];
  const float* betaq = (const float*)d_in[11];
  const float* mq    = (const float*)d_in[12];
  const float* vq    = (const float*)d_in[13];
  const float* wv    = (const float*)d_in[14];
  const float* bv    = (const float*)d_in[15];
  const float* wo    = (const float*)d_in[16];
  const float* bo    = (const float*)d_in[17];
  float* out = (float*)d_out;

  const size_t qkv = (size_t)NB * HW * CK;  // elems per bf16 tensor
  unsigned short* WqP  = (unsigned short*)d_ws;      // 32768 shorts
  unsigned short* WkvP = WqP + 32768;                // 65536 shorts
  unsigned short* WoP  = WkvP + 65536;               // 32768 shorts
  unsigned short* Qb   = WoP + 32768;
  unsigned short* Kb   = Qb + qkv;
  unsigned short* Vt   = Kb + qkv;
  unsigned short* OpartH = Vt + qkv;                 // bf16 partials
  const size_t fixed_bytes = 131072 * 2 + 3 * qkv * 2;

  prep_kernel<<<dim3(64), 256, 0, stream>>>(wq, wk, wv, wo, WqP, WkvP, WoP);
  proj_kernel<<<dim3(64, 4, 2), 256, 0, stream>>>(
      x_enc, x_dec, WqP, WkvP,
      bq, gq, betaq, mq, vq, bk, gk, betak, mk, vk, bv, Qb, Kb, Vt);

  auto need = [&](int nkc) {
    return fixed_bytes + (size_t)128 * nkc * 16384 * 2      // OpartH bf16
                       + (size_t)128 * nkc * 128 * 4;       // Ml fp32
  };
  if (ws_size >= need(8)) {
    float* Ml = (float*)(OpartH + (size_t)128 * 8 * 16384);
    attn_kernel8<8><<<dim3(512), 512, 0, stream>>>(Qb, Kb, Vt, OpartH, Ml);
    outproj_kernel<8><<<dim3(256, 4), 256, 0, stream>>>(OpartH, Ml, WoP, bo, out);
  } else if (ws_size >= need(4)) {
    float* Ml = (float*)(OpartH + (size_t)128 * 4 * 16384);
    attn_kernel8<4><<<dim3(256), 512, 0, stream>>>(Qb, Kb, Vt, OpartH, Ml);
    outproj_kernel<4><<<dim3(256, 4), 256, 0, stream>>>(OpartH, Ml, WoP, bo, out);
  } else if (ws_size >= need(2)) {
    float* Ml = (float*)(OpartH + (size_t)128 * 2 * 16384);
    attn_kernel8<2><<<dim3(128), 512, 0, stream>>>(Qb, Kb, Vt, OpartH, Ml);
    outproj_kernel<2><<<dim3(256, 4), 256, 0, stream>>>(OpartH, Ml, WoP, bo, out);
  } else {
    float* Ml = (float*)(OpartH + (size_t)128 * 1 * 16384);
    attn_kernel8<1><<<dim3(64), 512, 0, stream>>>(Qb, Kb, Vt, OpartH, Ml);
    outproj_kernel<1><<<dim3(256, 4), 256, 0, stream>>>(OpartH, Ml, WoP, bo, out);
  }
}

// Round 14
// 165.239 us; speedup vs baseline: 1.0999x; 1.0366x over previous
//
#include <hip/hip_runtime.h>

typedef __attribute__((ext_vector_type(8))) short short8;
typedef __attribute__((ext_vector_type(4))) float floatx4;

#define HW 4096
#define CIN 256
#define CK 128
#define COUT 256
#define NB 4
#define BN_EPS 1e-5f
// (1/sqrt(128)) * log2(e), folded into Q at projection time -> P = exp2(S)
#define SC2 0.12751744526f

#define MFMA(a, b, c) __builtin_amdgcn_mfma_f32_16x16x32_bf16((a), (b), (c), 0, 0, 0)

// f32 -> bf16, round-half-up (+0x8000). Differs from RNE only on exact ties;
// both are <=0.5 ulp from the fp32 value. 2 VALU ops.
__device__ __forceinline__ unsigned short f2bf(float f) {
  union { float f; unsigned u; } v; v.f = f;
  return (unsigned short)((v.u + 0x8000u) >> 16);
}

// pack {bf16(a) low, bf16(b) high} in 3 VALU ops: two rounding adds + one
// v_perm_b32 byte-select (D = [bu.3, bu.2, au.3, au.2] -> sel 0x07060302).
__device__ __forceinline__ unsigned pack2(float a, float b) {
  union { float f; unsigned u; } va, vb; va.f = a; vb.f = b;
  return __builtin_amdgcn_perm(vb.u + 0x8000u, va.u + 0x8000u, 0x07060302u);
}

__device__ __forceinline__ float bf2f(unsigned short u) {
  union { unsigned u; float f; } v; v.u = ((unsigned)u) << 16;
  return v.f;
}

__device__ __forceinline__ short8 pack8(const float* p) {
  union { unsigned u[4]; short8 s; } v;
  v.u[0] = pack2(p[0], p[1]);
  v.u[1] = pack2(p[2], p[3]);
  v.u[2] = pack2(p[4], p[5]);
  v.u[3] = pack2(p[6], p[7]);
  return v.s;
}

// ---------------------------------------------------------------------------
// Kernel 0: pre-pack weights as bf16 in MFMA A-fragment order (coalesced
// 16B/lane loads in proj/outproj).
// ---------------------------------------------------------------------------
__global__ __launch_bounds__(256) void prep_kernel(
    const float* __restrict__ wq, const float* __restrict__ wk,
    const float* __restrict__ wv, const float* __restrict__ wo,
    unsigned short* __restrict__ WqP, unsigned short* __restrict__ WkvP,
    unsigned short* __restrict__ WoP)
{
  const int t = blockIdx.x * 256 + threadIdx.x;  // 0..16383
  float tmp[8];
  if (t < 4096) {
    const int lane = t & 63, mt = (t >> 6) & 1, wave = (t >> 7) & 3, ks = t >> 9;
    const int lane16 = lane & 15, quad = lane >> 4;
    const int o = wave * 32 + mt * 16 + lane16;
    const float* src = wq + (size_t)o * CIN + ks * 32 + quad * 8;
    *(float4*)tmp = *(const float4*)src;
    *(float4*)(tmp + 4) = *(const float4*)(src + 4);
    *(short8*)&WqP[(size_t)t * 8] = pack8(tmp);
  } else if (t < 12288) {
    const int u = t - 4096;
    const int lane = u & 63, mt = (u >> 6) & 3, wave = (u >> 8) & 3, ks = u >> 10;
    const int lane16 = lane & 15, quad = lane >> 4;
    const int o = wave * 64 + mt * 16 + lane16;
    const float* row = (o < 128) ? wk + (size_t)o * CIN : wv + (size_t)(o - 128) * CIN;
    const float* src = row + ks * 32 + quad * 8;
    *(float4*)tmp = *(const float4*)src;
    *(float4*)(tmp + 4) = *(const float4*)(src + 4);
    *(short8*)&WkvP[(size_t)u * 8] = pack8(tmp);
  } else {
    const int u = t - 12288;
    const int lane = u & 63, mt = (u >> 6) & 3, wave = (u >> 8) & 3, ks = u >> 10;
    const int lane16 = lane & 15, quad = lane >> 4;
    const int o = wave * 64 + mt * 16 + lane16;
    const float* src = wo + (size_t)o * CK + ks * 32 + quad * 8;
    *(float4*)tmp = *(const float4*)src;
    *(float4*)(tmp + 4) = *(const float4*)(src + 4);
    *(short8*)&WoP[(size_t)u * 8] = pack8(tmp);
  }
}

// ---------------------------------------------------------------------------
// Kernel 1: projections. grid (64, 4, 2), block 256. (round-11 exact — the
// r13 qtr-prefetch regressed ~5 us and is removed.)
// ---------------------------------------------------------------------------
__global__ __launch_bounds__(256) void proj_kernel(
    const float* __restrict__ x_enc, const float* __restrict__ x_dec,
    const unsigned short* __restrict__ WqP, const unsigned short* __restrict__ WkvP,
    const float* __restrict__ bq, const float* __restrict__ gq,
    const float* __restrict__ betaq, const float* __restrict__ mq,
    const float* __restrict__ vq,
    const float* __restrict__ bk, const float* __restrict__ gk,
    const float* __restrict__ betak, const float* __restrict__ mk,
    const float* __restrict__ vk, const float* __restrict__ bv,
    unsigned short* __restrict__ Qb, unsigned short* __restrict__ Kb,
    unsigned short* __restrict__ Vt)
{
  const int tid = threadIdx.x;
  const int pt = blockIdx.x;
  const int b  = blockIdx.y;
  const int pj = blockIdx.z;

  const float* X = (pj == 0) ? x_dec : x_enc;

  __shared__ float xF[64 * 68];
  __shared__ unsigned short xT[64 * 264];

  const float* Xs = X + (size_t)b * CIN * HW + (size_t)pt * 64;
#pragma unroll
  for (int qtr = 0; qtr < 4; ++qtr) {
    if (qtr) __syncthreads();
    {
      const int c = tid >> 2;
      const int p0 = (tid & 3) * 16;
      const float* src = Xs + (size_t)(qtr * 64 + c) * HW + p0;
#pragma unroll
      for (int j = 0; j < 4; ++j)
        *(float4*)&xF[c * 68 + p0 + j * 4] = *(const float4*)(src + j * 4);
    }
    __syncthreads();
    {
      const int p = tid & 63;
      const int cb = tid >> 6;
#pragma unroll
      for (int jj = 0; jj < 2; ++jj) {
        const int c0 = (jj * 4 + cb) * 8;
        float t[8];
#pragma unroll
        for (int u = 0; u < 8; ++u) t[u] = xF[(c0 + u) * 68 + p];
        *(short8*)&xT[p * 264 + qtr * 64 + c0] = pack8(t);
      }
    }
  }
  __syncthreads();

  const int wave = tid >> 6;
  const int lane = tid & 63;
  const int lane16 = lane & 15;
  const int quad = lane >> 4;

  if (pj == 0) {
    floatx4 acc[2][4];
#pragma unroll
    for (int mt = 0; mt < 2; ++mt)
#pragma unroll
      for (int nf = 0; nf < 4; ++nf) acc[mt][nf] = (floatx4){0.f, 0.f, 0.f, 0.f};

#pragma unroll
    for (int ks = 0; ks < 8; ++ks) {
      short8 af[2];
#pragma unroll
      for (int mt = 0; mt < 2; ++mt)
        af[mt] = *(const short8*)&WqP[(size_t)((((ks * 4 + wave) * 2 + mt) * 64) + lane) * 8];
#pragma unroll
      for (int nf = 0; nf < 4; ++nf) {
        const short8 bf = *(const short8*)&xT[(nf * 16 + lane16) * 264 + ks * 32 + quad * 8];
#pragma unroll
        for (int mt = 0; mt < 2; ++mt) acc[mt][nf] = MFMA(af[mt], bf, acc[mt][nf]);
      }
    }

    float sc[2][4], off[2][4];
#pragma unroll
    for (int mt = 0; mt < 2; ++mt)
#pragma unroll
      for (int r = 0; r < 4; ++r) {
        const int o = wave * 32 + mt * 16 + quad * 4 + r;
        const float s = gq[o] * rsqrtf(vq[o] + BN_EPS) * SC2;
        sc[mt][r] = s;
        off[mt][r] = (bq[o] - mq[o]) * s + betaq[o] * SC2;
      }
#pragma unroll
    for (int nf = 0; nf < 4; ++nf) {
      const size_t prow = ((size_t)b * HW + pt * 64 + nf * 16 + lane16) * CK;
#pragma unroll
      for (int mt = 0; mt < 2; ++mt) {
        const unsigned lo = pack2(fmaxf(acc[mt][nf][0] * sc[mt][0] + off[mt][0], 0.f),
                                  fmaxf(acc[mt][nf][1] * sc[mt][1] + off[mt][1], 0.f));
        const unsigned hi = pack2(fmaxf(acc[mt][nf][2] * sc[mt][2] + off[mt][2], 0.f),
                                  fmaxf(acc[mt][nf][3] * sc[mt][3] + off[mt][3], 0.f));
        *(uint2*)(Qb + prow + wave * 32 + mt * 16 + quad * 4) = make_uint2(lo, hi);
      }
    }
  } else {
    const bool isK = (wave < 2);
    floatx4 acc[4][4];
#pragma unroll
    for (int mt = 0; mt < 4; ++mt)
#pragma unroll
      for (int nf = 0; nf < 4; ++nf) acc[mt][nf] = (floatx4){0.f, 0.f, 0.f, 0.f};

#pragma unroll
    for (int ks = 0; ks < 8; ++ks) {
      short8 af[4];
#pragma unroll
      for (int mt = 0; mt < 4; ++mt)
        af[mt] = *(const short8*)&WkvP[(size_t)((((ks * 4 + wave) * 4 + mt) * 64) + lane) * 8];
#pragma unroll
      for (int nf = 0; nf < 4; ++nf) {
        const short8 bf = *(const short8*)&xT[(nf * 16 + lane16) * 264 + ks * 32 + quad * 8];
#pragma unroll
        for (int mt = 0; mt < 4; ++mt) acc[mt][nf] = MFMA(af[mt], bf, acc[mt][nf]);
      }
    }

    if (isK) {
      float sc[4][4], off[4][4];
#pragma unroll
      for (int mt = 0; mt < 4; ++mt)
#pragma unroll
        for (int r = 0; r < 4; ++r) {
          const int o = wave * 64 + mt * 16 + quad * 4 + r;
          const float s = gk[o] * rsqrtf(vk[o] + BN_EPS);
          sc[mt][r] = s;
          off[mt][r] = (bk[o] - mk[o]) * s + betak[o];
        }
#pragma unroll
      for (int nf = 0; nf < 4; ++nf) {
        const size_t prow = ((size_t)b * HW + pt * 64 + nf * 16 + lane16) * CK;
#pragma unroll
        for (int mt = 0; mt < 4; ++mt) {
          const unsigned lo = pack2(fmaxf(acc[mt][nf][0] * sc[mt][0] + off[mt][0], 0.f),
                                    fmaxf(acc[mt][nf][1] * sc[mt][1] + off[mt][1], 0.f));
          const unsigned hi = pack2(fmaxf(acc[mt][nf][2] * sc[mt][2] + off[mt][2], 0.f),
                                    fmaxf(acc[mt][nf][3] * sc[mt][3] + off[mt][3], 0.f));
          *(uint2*)(Kb + prow + wave * 64 + mt * 16 + quad * 4) = make_uint2(lo, hi);
        }
      }
    } else {
#pragma unroll
      for (int mt = 0; mt < 4; ++mt) {
#pragma unroll
        for (int r = 0; r < 4; ++r) {
          const int c = wave * 64 + mt * 16 + quad * 4 + r - 128;
          const float bias = bv[c];
          unsigned short* dst = Vt + ((size_t)(b * CK + c)) * HW + pt * 64;
#pragma unroll
          for (int nf = 0; nf < 4; ++nf)
            dst[nf * 16 + lane16] = f2bf(acc[mt][nf][r] + bias);
        }
      }
    }
  }
}

// ---------------------------------------------------------------------------
// Kernel 2: split-K flash attention — round-11 exact (measured 44.6 us):
// 8-wave blocks, in-register P (sigma row permutation), double-buffered
// Kl/Vl, one barrier/iter, write-late staging, 3-op perm pack, no stagger.
// grid 64*NKC (b=blk&3, qt=(blk>>2)&15, kc=blk>>6), block 512 (8 waves).
// ---------------------------------------------------------------------------
template<int NKC>
__global__ __launch_bounds__(512) void attn_kernel8(
    const unsigned short* __restrict__ Qb, const unsigned short* __restrict__ Kb,
    const unsigned short* __restrict__ Vt, unsigned short* __restrict__ OpartH,
    float* __restrict__ Ml)
{
  constexpr int ITERS = 64 / NKC;
  const int tid = threadIdx.x;
  const int blk = blockIdx.x;
  const int b  = blk & 3;
  const int qt = (blk >> 2) & 15;
  const int kc = blk >> 6;

  const int wave = tid >> 6;
  const int lane = tid & 63;
  const int lane16 = lane & 15;
  const int quad = lane >> 4;

  __shared__ unsigned short Kl[2][64 * 136];  // [buf][slot][c], stride 136
  __shared__ unsigned short Vl[2][128 * 72];  // [buf][c][kp], stride 72

  const int q0 = qt * 256 + wave * 32;
  short8 qf[2][4];
  {
    const unsigned short* Qs = Qb + ((size_t)b * HW + q0) * CK;
#pragma unroll
    for (int mt = 0; mt < 2; ++mt)
#pragma unroll
      for (int ks = 0; ks < 4; ++ks)
        qf[mt][ks] = *(const short8*)(Qs + (size_t)(mt * 16 + lane16) * CK + ks * 32 + quad * 8);
  }

  short8 ones;
#pragma unroll
  for (int i = 0; i < 8; ++i) ones[i] = (short)0x3F80;  // bf16 1.0

  floatx4 O[2][8];
  floatx4 Lacc[2];
#pragma unroll
  for (int mt = 0; mt < 2; ++mt) {
    Lacc[mt] = (floatx4){0.f, 0.f, 0.f, 0.f};
#pragma unroll
    for (int nf = 0; nf < 8; ++nf) O[mt][nf] = (floatx4){0.f, 0.f, 0.f, 0.f};
  }

  const int krow = tid >> 4;           // 0..31
  const int kcol = (tid & 15) * 8;     // shorts
  const int vrow = tid >> 2;           // 0..127 (channel)
  const int vcol = (tid & 3) * 16;     // shorts

  // staging slots for the 2 K rows this thread writes (g = krow + 32*i2)
  int kslot[2];
#pragma unroll
  for (int i2 = 0; i2 < 2; ++i2) {
    const int g = krow + i2 * 32;
    kslot[i2] = (g & 0x23) | ((g & 0x18) >> 1) | ((g & 0x04) << 2);
  }

  const unsigned short* Kg = Kb + ((size_t)b * HW + (size_t)kc * ITERS * 64) * CK;
  const unsigned short* Vg = Vt + (size_t)b * CK * HW + kc * ITERS * 64;

  short8 kr[2], vr[2];
#pragma unroll
  for (int i2 = 0; i2 < 2; ++i2)
    kr[i2] = *(const short8*)(Kg + (size_t)(krow + i2 * 32) * CK + kcol);
#pragma unroll
  for (int i2 = 0; i2 < 2; ++i2)
    vr[i2] = *(const short8*)(Vg + (size_t)vrow * HW + vcol + i2 * 8);

  // prologue: tile 0 into buffer 0
#pragma unroll
  for (int i2 = 0; i2 < 2; ++i2)
    *(short8*)&Kl[0][kslot[i2] * 136 + kcol] = kr[i2];
#pragma unroll
  for (int i2 = 0; i2 < 2; ++i2)
    *(short8*)&Vl[0][vrow * 72 + vcol + i2 * 8] = vr[i2];
  __syncthreads();

  for (int it = 0; it < ITERS; ++it) {
    const int cur = it & 1;
    const unsigned short* Klc = &Kl[cur][0];
    const unsigned short* Vlc = &Vl[cur][0];

    if (it + 1 < ITERS) {  // issue prefetch of tile t+1 (lands during compute)
      const unsigned short* Kn = Kg + (size_t)((it + 1) * 64) * CK;
      const unsigned short* Vn = Vg + (it + 1) * 64;
#pragma unroll
      for (int i2 = 0; i2 < 2; ++i2)
        kr[i2] = *(const short8*)(Kn + (size_t)(krow + i2 * 32) * CK + kcol);
#pragma unroll
      for (int i2 = 0; i2 < 2; ++i2)
        vr[i2] = *(const short8*)(Vn + (size_t)vrow * HW + vcol + i2 * 8);
    }

    __builtin_amdgcn_s_setprio(1);
    // Per 32-wide PV k-chunk: QK^T on tile pair (2kp, 2kp+1) -> exp2/pack
    // in-register -> PV straight from the packed A-frag. No LDS for P.
#pragma unroll
    for (int kp = 0; kp < 2; ++kp) {
      floatx4 sA0 = (floatx4){0.f, 0.f, 0.f, 0.f};
      floatx4 sA1 = (floatx4){0.f, 0.f, 0.f, 0.f};
      floatx4 sB0 = (floatx4){0.f, 0.f, 0.f, 0.f};
      floatx4 sB1 = (floatx4){0.f, 0.f, 0.f, 0.f};
#pragma unroll
      for (int ks = 0; ks < 4; ++ks) {
        const short8 kfA = *(const short8*)&Klc[((2 * kp) * 16 + lane16) * 136 + ks * 32 + quad * 8];
        const short8 kfB = *(const short8*)&Klc[((2 * kp + 1) * 16 + lane16) * 136 + ks * 32 + quad * 8];
        sA0 = MFMA(kfA, qf[0][ks], sA0);
        sA1 = MFMA(kfA, qf[1][ks], sA1);
        sB0 = MFMA(kfB, qf[0][ks], sB0);
        sB1 = MFMA(kfB, qf[1][ks], sB1);
      }
      union { unsigned u[4]; short8 s; } pf0, pf1;
      pf0.u[0] = pack2(__builtin_amdgcn_exp2f(sA0[0]), __builtin_amdgcn_exp2f(sA0[1]));
      pf0.u[1] = pack2(__builtin_amdgcn_exp2f(sA0[2]), __builtin_amdgcn_exp2f(sA0[3]));
      pf0.u[2] = pack2(__builtin_amdgcn_exp2f(sB0[0]), __builtin_amdgcn_exp2f(sB0[1]));
      pf0.u[3] = pack2(__builtin_amdgcn_exp2f(sB0[2]), __builtin_amdgcn_exp2f(sB0[3]));
      pf1.u[0] = pack2(__builtin_amdgcn_exp2f(sA1[0]), __builtin_amdgcn_exp2f(sA1[1]));
      pf1.u[1] = pack2(__builtin_amdgcn_exp2f(sA1[2]), __builtin_amdgcn_exp2f(sA1[3]));
      pf1.u[2] = pack2(__builtin_amdgcn_exp2f(sB1[0]), __builtin_amdgcn_exp2f(sB1[1]));
      pf1.u[3] = pack2(__builtin_amdgcn_exp2f(sB1[2]), __builtin_amdgcn_exp2f(sB1[3]));

      Lacc[0] = MFMA(pf0.s, ones, Lacc[0]);
      Lacc[1] = MFMA(pf1.s, ones, Lacc[1]);
#pragma unroll
      for (int nf = 0; nf < 8; ++nf) {
        const short8 vf = *(const short8*)&Vlc[(nf * 16 + lane16) * 72 + kp * 32 + quad * 8];
        O[0][nf] = MFMA(pf0.s, vf, O[0][nf]);
        O[1][nf] = MFMA(pf1.s, vf, O[1][nf]);
      }
    }
    __builtin_amdgcn_s_setprio(0);

    if (it + 1 < ITERS) {  // write-late: stage tile t+1 into the other buffer
      const int nxt = cur ^ 1;
#pragma unroll
      for (int i2 = 0; i2 < 2; ++i2)
        *(short8*)&Kl[nxt][kslot[i2] * 136 + kcol] = kr[i2];
#pragma unroll
      for (int i2 = 0; i2 < 2; ++i2)
        *(short8*)&Vl[nxt][vrow * 72 + vcol + i2 * 8] = vr[i2];
    }
    __syncthreads();
  }

  // epilogue: bf16 unnormalized partial O + fp32 l. Waves 0-3 -> even
  // 128-row chunk (qt*2), waves 4-7 -> odd chunk (qt*2+1); row uses wave&3.
  const int qt128 = qt * 2 + (wave >> 2);
  const int w4 = wave & 3;
  const int chunk = (b * 32 + qt128) * NKC + kc;
  unsigned short* Op = OpartH + (size_t)chunk * (128 * 128);
#pragma unroll
  for (int mt = 0; mt < 2; ++mt)
#pragma unroll
    for (int nf = 0; nf < 8; ++nf)
#pragma unroll
      for (int r = 0; r < 4; ++r)
        Op[(size_t)(w4 * 32 + mt * 16 + quad * 4 + r) * 128 + nf * 16 + lane16] =
            f2bf(O[mt][nf][r]);
  if (lane16 == 0) {
    float* Mp = Ml + (size_t)chunk * 128 + w4 * 32;
#pragma unroll
    for (int mt = 0; mt < 2; ++mt)
#pragma unroll
      for (int r = 0; r < 4; ++r)
        Mp[mt * 16 + quad * 4 + r] = Lacc[mt][r];
  }
}

// ---------------------------------------------------------------------------
// Kernel 3: fused combine + out-projection (bf16 partials, packed WoP).
// grid (256 p-tiles of 16, 4 batch), block 256. (round-11 exact)
// ---------------------------------------------------------------------------
template<int NKC>
__global__ __launch_bounds__(256) void outproj_kernel(
    const unsigned short* __restrict__ OpartH, const float* __restrict__ Ml,
    const unsigned short* __restrict__ WoP, const float* __restrict__ bo,
    float* __restrict__ out)
{
  const int tid = threadIdx.x;
  const int pt = blockIdx.x;
  const int b  = blockIdx.y;
  const int qt = pt >> 3;
  const int q0 = (pt & 7) * 16;
  const int chunk0 = (b * 32 + qt) * NKC;

  __shared__ unsigned short Ctile[16 * 136];

  {
    const int row = tid >> 4;
    const int c8  = (tid & 15) * 8;
    float L = 0.f;
#pragma unroll
    for (int k = 0; k < NKC; ++k) L += Ml[(size_t)(chunk0 + k) * 128 + q0 + row];
    float acc[8];
#pragma unroll
    for (int i = 0; i < 8; ++i) acc[i] = 0.f;
#pragma unroll
    for (int k = 0; k < NKC; ++k) {
      const short8 v = *(const short8*)(OpartH + (size_t)(chunk0 + k) * 16384 +
                                        (size_t)(q0 + row) * 128 + c8);
#pragma unroll
      for (int i = 0; i < 8; ++i) acc[i] += bf2f((unsigned short)v[i]);
    }
    const float inv = 1.f / L;
#pragma unroll
    for (int i = 0; i < 8; ++i) acc[i] *= inv;
    *(short8*)&Ctile[row * 136 + c8] = pack8(acc);
  }
  __syncthreads();

  const int wave = tid >> 6;
  const int lane = tid & 63;
  const int lane16 = lane & 15;
  const int quad = lane >> 4;

  floatx4 acc[4];
#pragma unroll
  for (int mt = 0; mt < 4; ++mt) acc[mt] = (floatx4){0.f, 0.f, 0.f, 0.f};

#pragma unroll
  for (int ks = 0; ks < 4; ++ks) {
    const short8 bf = *(const short8*)&Ctile[lane16 * 136 + ks * 32 + quad * 8];
#pragma unroll
    for (int mt = 0; mt < 4; ++mt) {
      const short8 af = *(const short8*)&WoP[(size_t)((((ks * 4 + wave) * 4 + mt) * 64) + lane) * 8];
      acc[mt] = MFMA(af, bf, acc[mt]);
    }
  }

#pragma unroll
  for (int mt = 0; mt < 4; ++mt) {
#pragma unroll
    for (int r = 0; r < 4; ++r) {
      const int o = wave * 64 + mt * 16 + quad * 4 + r;
      float* dst = out + ((size_t)b * COUT + o) * HW + qt * 128 + q0;
      dst[lane16] = acc[mt][r] + bo[o];
    }
  }
}

extern "C" void kernel_launch(void* const* d_in, const int* in_sizes, int n_in,
                              void* d_out, int out_size, void* d_ws, size_t ws_size,
                              hipStream_t stream)
{
  (void)in_sizes; (void)n_in; (void)out_size;
  const float* x_enc = (const float*)d_in[0];
  const float* x_dec = (const float*)d_in[1];
  const float* wk    = (const float*)d_in[2];
  const float* bk    = (const float*)d_in[3];
  const float* gk    = (const float*)d_in[4];
  const float* betak = (const float*)d_in[5];
  const float* mk    = (const float*)d_in[6];
  const float* vk    = (const float*)d_in[7];
  const float* wq    = (const float*)d_in[8];
  const float* bq    = (const float*)d_in[9];
  const float* gq    = (const float*)d_in[10];
  const float* betaq = (const float*)d_in[11];
  const float* mq    = (const float*)d_in[12];
  const float* vq    = (const float*)d_in[13];
  const float* wv    = (const float*)d_in[14];
  const float* bv    = (const float*)d_in[15];
  const float* wo    = (const float*)d_in[16];
  const float* bo    = (const float*)d_in[17];
  float* out = (float*)d_out;

  const size_t qkv = (size_t)NB * HW * CK;  // elems per bf16 tensor
  unsigned short* WqP  = (unsigned short*)d_ws;      // 32768 shorts
  unsigned short* WkvP = WqP + 32768;                // 65536 shorts
  unsigned short* WoP  = WkvP + 65536;               // 32768 shorts
  unsigned short* Qb   = WoP + 32768;
  unsigned short* Kb   = Qb + qkv;
  unsigned short* Vt   = Kb + qkv;
  unsigned short* OpartH = Vt + qkv;                 // bf16 partials
  const size_t fixed_bytes = 131072 * 2 + 3 * qkv * 2;

  prep_kernel<<<dim3(64), 256, 0, stream>>>(wq, wk, wv, wo, WqP, WkvP, WoP);
  proj_kernel<<<dim3(64, 4, 2), 256, 0, stream>>>(
      x_enc, x_dec, WqP, WkvP,
      bq, gq, betaq, mq, vq, bk, gk, betak, mk, vk, bv, Qb, Kb, Vt);

  auto need = [&](int nkc) {
    return fixed_bytes + (size_t)128 * nkc * 16384 * 2      // OpartH bf16
                       + (size_t)128 * nkc * 128 * 4;       // Ml fp32
  };
  if (ws_size >= need(8)) {
    float* Ml = (float*)(OpartH + (size_t)128 * 8 * 16384);
    attn_kernel8<8><<<dim3(512), 512, 0, stream>>>(Qb, Kb, Vt, OpartH, Ml);
    outproj_kernel<8><<<dim3(256, 4), 256, 0, stream>>>(OpartH, Ml, WoP, bo, out);
  } else if (ws_size >= need(4)) {
    float* Ml = (float*)(OpartH + (size_t)128 * 4 * 16384);
    attn_kernel8<4><<<dim3(256), 512, 0, stream>>>(Qb, Kb, Vt, OpartH, Ml);
    outproj_kernel<4><<<dim3(256, 4), 256, 0, stream>>>(OpartH, Ml, WoP, bo, out);
  } else if (ws_size >= need(2)) {
    float* Ml = (float*)(OpartH + (size_t)128 * 2 * 16384);
    attn_kernel8<2><<<dim3(128), 512, 0, stream>>>(Qb, Kb, Vt, OpartH, Ml);
    outproj_kernel<2><<<dim3(256, 4), 256, 0, stream>>>(OpartH, Ml, WoP, bo, out);
  } else {
    float* Ml = (float*)(OpartH + (size_t)128 * 1 * 16384);
    attn_kernel8<1><<<dim3(64), 512, 0, stream>>>(Qb, Kb, Vt, OpartH, Ml);
    outproj_kernel<1><<<dim3(256, 4), 256, 0, stream>>>(OpartH, Ml, WoP, bo, out);
  }
}

// Round 15
// 163.555 us; speedup vs baseline: 1.1112x; 1.0103x over previous
//
#include <hip/hip_runtime.h>

typedef __attribute__((ext_vector_type(8))) short short8;
typedef __attribute__((ext_vector_type(4))) float floatx4;

#define HW 4096
#define CIN 256
#define CK 128
#define COUT 256
#define NB 4
#define BN_EPS 1e-5f
// (1/sqrt(128)) * log2(e), folded into Q at projection time -> P = exp2(S)
#define SC2 0.12751744526f

#define MFMA(a, b, c) __builtin_amdgcn_mfma_f32_16x16x32_bf16((a), (b), (c), 0, 0, 0)

// f32 -> bf16, round-half-up (+0x8000). Differs from RNE only on exact ties;
// both are <=0.5 ulp from the fp32 value. 2 VALU ops.
__device__ __forceinline__ unsigned short f2bf(float f) {
  union { float f; unsigned u; } v; v.f = f;
  return (unsigned short)((v.u + 0x8000u) >> 16);
}

// pack {bf16(a) low, bf16(b) high} in 3 VALU ops: two rounding adds + one
// v_perm_b32 byte-select (D = [bu.3, bu.2, au.3, au.2] -> sel 0x07060302).
__device__ __forceinline__ unsigned pack2(float a, float b) {
  union { float f; unsigned u; } va, vb; va.f = a; vb.f = b;
  return __builtin_amdgcn_perm(vb.u + 0x8000u, va.u + 0x8000u, 0x07060302u);
}

__device__ __forceinline__ float bf2f(unsigned short u) {
  union { unsigned u; float f; } v; v.u = ((unsigned)u) << 16;
  return v.f;
}

__device__ __forceinline__ short8 pack8(const float* p) {
  union { unsigned u[4]; short8 s; } v;
  v.u[0] = pack2(p[0], p[1]);
  v.u[1] = pack2(p[2], p[3]);
  v.u[2] = pack2(p[4], p[5]);
  v.u[3] = pack2(p[6], p[7]);
  return v.s;
}

// ---------------------------------------------------------------------------
// Kernel 0: pre-pack weights as bf16 in MFMA A-fragment order (coalesced
// 16B/lane loads in proj/outproj).
// ---------------------------------------------------------------------------
__global__ __launch_bounds__(256) void prep_kernel(
    const float* __restrict__ wq, const float* __restrict__ wk,
    const float* __restrict__ wv, const float* __restrict__ wo,
    unsigned short* __restrict__ WqP, unsigned short* __restrict__ WkvP,
    unsigned short* __restrict__ WoP)
{
  const int t = blockIdx.x * 256 + threadIdx.x;  // 0..16383
  float tmp[8];
  if (t < 4096) {
    const int lane = t & 63, mt = (t >> 6) & 1, wave = (t >> 7) & 3, ks = t >> 9;
    const int lane16 = lane & 15, quad = lane >> 4;
    const int o = wave * 32 + mt * 16 + lane16;
    const float* src = wq + (size_t)o * CIN + ks * 32 + quad * 8;
    *(float4*)tmp = *(const float4*)src;
    *(float4*)(tmp + 4) = *(const float4*)(src + 4);
    *(short8*)&WqP[(size_t)t * 8] = pack8(tmp);
  } else if (t < 12288) {
    const int u = t - 4096;
    const int lane = u & 63, mt = (u >> 6) & 3, wave = (u >> 8) & 3, ks = u >> 10;
    const int lane16 = lane & 15, quad = lane >> 4;
    const int o = wave * 64 + mt * 16 + lane16;
    const float* row = (o < 128) ? wk + (size_t)o * CIN : wv + (size_t)(o - 128) * CIN;
    const float* src = row + ks * 32 + quad * 8;
    *(float4*)tmp = *(const float4*)src;
    *(float4*)(tmp + 4) = *(const float4*)(src + 4);
    *(short8*)&WkvP[(size_t)u * 8] = pack8(tmp);
  } else {
    const int u = t - 12288;
    const int lane = u & 63, mt = (u >> 6) & 3, wave = (u >> 8) & 3, ks = u >> 10;
    const int lane16 = lane & 15, quad = lane >> 4;
    const int o = wave * 64 + mt * 16 + lane16;
    const float* src = wo + (size_t)o * CK + ks * 32 + quad * 8;
    *(float4*)tmp = *(const float4*)src;
    *(float4*)(tmp + 4) = *(const float4*)(src + 4);
    *(short8*)&WoP[(size_t)u * 8] = pack8(tmp);
  }
}

// ---------------------------------------------------------------------------
// Kernel 1: projections. grid (64, 4, 2), block 256. (round-11 exact)
// ---------------------------------------------------------------------------
__global__ __launch_bounds__(256) void proj_kernel(
    const float* __restrict__ x_enc, const float* __restrict__ x_dec,
    const unsigned short* __restrict__ WqP, const unsigned short* __restrict__ WkvP,
    const float* __restrict__ bq, const float* __restrict__ gq,
    const float* __restrict__ betaq, const float* __restrict__ mq,
    const float* __restrict__ vq,
    const float* __restrict__ bk, const float* __restrict__ gk,
    const float* __restrict__ betak, const float* __restrict__ mk,
    const float* __restrict__ vk, const float* __restrict__ bv,
    unsigned short* __restrict__ Qb, unsigned short* __restrict__ Kb,
    unsigned short* __restrict__ Vt)
{
  const int tid = threadIdx.x;
  const int pt = blockIdx.x;
  const int b  = blockIdx.y;
  const int pj = blockIdx.z;

  const float* X = (pj == 0) ? x_dec : x_enc;

  __shared__ float xF[64 * 68];
  __shared__ unsigned short xT[64 * 264];

  const float* Xs = X + (size_t)b * CIN * HW + (size_t)pt * 64;
#pragma unroll
  for (int qtr = 0; qtr < 4; ++qtr) {
    if (qtr) __syncthreads();
    {
      const int c = tid >> 2;
      const int p0 = (tid & 3) * 16;
      const float* src = Xs + (size_t)(qtr * 64 + c) * HW + p0;
#pragma unroll
      for (int j = 0; j < 4; ++j)
        *(float4*)&xF[c * 68 + p0 + j * 4] = *(const float4*)(src + j * 4);
    }
    __syncthreads();
    {
      const int p = tid & 63;
      const int cb = tid >> 6;
#pragma unroll
      for (int jj = 0; jj < 2; ++jj) {
        const int c0 = (jj * 4 + cb) * 8;
        float t[8];
#pragma unroll
        for (int u = 0; u < 8; ++u) t[u] = xF[(c0 + u) * 68 + p];
        *(short8*)&xT[p * 264 + qtr * 64 + c0] = pack8(t);
      }
    }
  }
  __syncthreads();

  const int wave = tid >> 6;
  const int lane = tid & 63;
  const int lane16 = lane & 15;
  const int quad = lane >> 4;

  if (pj == 0) {
    floatx4 acc[2][4];
#pragma unroll
    for (int mt = 0; mt < 2; ++mt)
#pragma unroll
      for (int nf = 0; nf < 4; ++nf) acc[mt][nf] = (floatx4){0.f, 0.f, 0.f, 0.f};

#pragma unroll
    for (int ks = 0; ks < 8; ++ks) {
      short8 af[2];
#pragma unroll
      for (int mt = 0; mt < 2; ++mt)
        af[mt] = *(const short8*)&WqP[(size_t)((((ks * 4 + wave) * 2 + mt) * 64) + lane) * 8];
#pragma unroll
      for (int nf = 0; nf < 4; ++nf) {
        const short8 bf = *(const short8*)&xT[(nf * 16 + lane16) * 264 + ks * 32 + quad * 8];
#pragma unroll
        for (int mt = 0; mt < 2; ++mt) acc[mt][nf] = MFMA(af[mt], bf, acc[mt][nf]);
      }
    }

    float sc[2][4], off[2][4];
#pragma unroll
    for (int mt = 0; mt < 2; ++mt)
#pragma unroll
      for (int r = 0; r < 4; ++r) {
        const int o = wave * 32 + mt * 16 + quad * 4 + r;
        const float s = gq[o] * rsqrtf(vq[o] + BN_EPS) * SC2;
        sc[mt][r] = s;
        off[mt][r] = (bq[o] - mq[o]) * s + betaq[o] * SC2;
      }
#pragma unroll
    for (int nf = 0; nf < 4; ++nf) {
      const size_t prow = ((size_t)b * HW + pt * 64 + nf * 16 + lane16) * CK;
#pragma unroll
      for (int mt = 0; mt < 2; ++mt) {
        const unsigned lo = pack2(fmaxf(acc[mt][nf][0] * sc[mt][0] + off[mt][0], 0.f),
                                  fmaxf(acc[mt][nf][1] * sc[mt][1] + off[mt][1], 0.f));
        const unsigned hi = pack2(fmaxf(acc[mt][nf][2] * sc[mt][2] + off[mt][2], 0.f),
                                  fmaxf(acc[mt][nf][3] * sc[mt][3] + off[mt][3], 0.f));
        *(uint2*)(Qb + prow + wave * 32 + mt * 16 + quad * 4) = make_uint2(lo, hi);
      }
    }
  } else {
    const bool isK = (wave < 2);
    floatx4 acc[4][4];
#pragma unroll
    for (int mt = 0; mt < 4; ++mt)
#pragma unroll
      for (int nf = 0; nf < 4; ++nf) acc[mt][nf] = (floatx4){0.f, 0.f, 0.f, 0.f};

#pragma unroll
    for (int ks = 0; ks < 8; ++ks) {
      short8 af[4];
#pragma unroll
      for (int mt = 0; mt < 4; ++mt)
        af[mt] = *(const short8*)&WkvP[(size_t)((((ks * 4 + wave) * 4 + mt) * 64) + lane) * 8];
#pragma unroll
      for (int nf = 0; nf < 4; ++nf) {
        const short8 bf = *(const short8*)&xT[(nf * 16 + lane16) * 264 + ks * 32 + quad * 8];
#pragma unroll
        for (int mt = 0; mt < 4; ++mt) acc[mt][nf] = MFMA(af[mt], bf, acc[mt][nf]);
      }
    }

    if (isK) {
      float sc[4][4], off[4][4];
#pragma unroll
      for (int mt = 0; mt < 4; ++mt)
#pragma unroll
        for (int r = 0; r < 4; ++r) {
          const int o = wave * 64 + mt * 16 + quad * 4 + r;
          const float s = gk[o] * rsqrtf(vk[o] + BN_EPS);
          sc[mt][r] = s;
          off[mt][r] = (bk[o] - mk[o]) * s + betak[o];
        }
#pragma unroll
      for (int nf = 0; nf < 4; ++nf) {
        const size_t prow = ((size_t)b * HW + pt * 64 + nf * 16 + lane16) * CK;
#pragma unroll
        for (int mt = 0; mt < 4; ++mt) {
          const unsigned lo = pack2(fmaxf(acc[mt][nf][0] * sc[mt][0] + off[mt][0], 0.f),
                                    fmaxf(acc[mt][nf][1] * sc[mt][1] + off[mt][1], 0.f));
          const unsigned hi = pack2(fmaxf(acc[mt][nf][2] * sc[mt][2] + off[mt][2], 0.f),
                                    fmaxf(acc[mt][nf][3] * sc[mt][3] + off[mt][3], 0.f));
          *(uint2*)(Kb + prow + wave * 64 + mt * 16 + quad * 4) = make_uint2(lo, hi);
        }
      }
    } else {
#pragma unroll
      for (int mt = 0; mt < 4; ++mt) {
#pragma unroll
        for (int r = 0; r < 4; ++r) {
          const int c = wave * 64 + mt * 16 + quad * 4 + r - 128;
          const float bias = bv[c];
          unsigned short* dst = Vt + ((size_t)(b * CK + c)) * HW + pt * 64;
#pragma unroll
          for (int nf = 0; nf < 4; ++nf)
            dst[nf * 16 + lane16] = f2bf(acc[mt][nf][r] + bias);
        }
      }
    }
  }
}

// ---------------------------------------------------------------------------
// Kernel 2: split-K flash attention — round-11 structure (44.4 us) with ONE
// change: the L row-sum is no longer computed via MFMA(pf, ones). Each
// lane's 8 exp2 outputs per kp are exactly P[q][k = kp*32 + quad*8 + 0..7],
// so L[q] = per-lane fp32 accumulation + a 2-step __shfl_xor(16/32) quad
// reduce in the EPILOGUE only. Removes 4 of 68 MFMAs/iter from the
// dependent post-exp2 cluster; fp32 L is numerically closer to the fp32
// reference softmax denominator than the old bf16-P sum.
// grid 64*NKC (b=blk&3, qt=(blk>>2)&15, kc=blk>>6), block 512 (8 waves).
// ---------------------------------------------------------------------------
template<int NKC>
__global__ __launch_bounds__(512) void attn_kernel8(
    const unsigned short* __restrict__ Qb, const unsigned short* __restrict__ Kb,
    const unsigned short* __restrict__ Vt, unsigned short* __restrict__ OpartH,
    float* __restrict__ Ml)
{
  constexpr int ITERS = 64 / NKC;
  const int tid = threadIdx.x;
  const int blk = blockIdx.x;
  const int b  = blk & 3;
  const int qt = (blk >> 2) & 15;
  const int kc = blk >> 6;

  const int wave = tid >> 6;
  const int lane = tid & 63;
  const int lane16 = lane & 15;
  const int quad = lane >> 4;

  __shared__ unsigned short Kl[2][64 * 136];  // [buf][slot][c], stride 136
  __shared__ unsigned short Vl[2][128 * 72];  // [buf][c][kp], stride 72

  const int q0 = qt * 256 + wave * 32;
  short8 qf[2][4];
  {
    const unsigned short* Qs = Qb + ((size_t)b * HW + q0) * CK;
#pragma unroll
    for (int mt = 0; mt < 2; ++mt)
#pragma unroll
      for (int ks = 0; ks < 4; ++ks)
        qf[mt][ks] = *(const short8*)(Qs + (size_t)(mt * 16 + lane16) * CK + ks * 32 + quad * 8);
  }

  floatx4 O[2][8];
  float lsum0 = 0.f, lsum1 = 0.f;   // per-lane partial row sums (q=l16, q=l16+16)
#pragma unroll
  for (int mt = 0; mt < 2; ++mt)
#pragma unroll
    for (int nf = 0; nf < 8; ++nf) O[mt][nf] = (floatx4){0.f, 0.f, 0.f, 0.f};

  const int krow = tid >> 4;           // 0..31
  const int kcol = (tid & 15) * 8;     // shorts
  const int vrow = tid >> 2;           // 0..127 (channel)
  const int vcol = (tid & 3) * 16;     // shorts

  // staging slots for the 2 K rows this thread writes (g = krow + 32*i2)
  int kslot[2];
#pragma unroll
  for (int i2 = 0; i2 < 2; ++i2) {
    const int g = krow + i2 * 32;
    kslot[i2] = (g & 0x23) | ((g & 0x18) >> 1) | ((g & 0x04) << 2);
  }

  const unsigned short* Kg = Kb + ((size_t)b * HW + (size_t)kc * ITERS * 64) * CK;
  const unsigned short* Vg = Vt + (size_t)b * CK * HW + kc * ITERS * 64;

  short8 kr[2], vr[2];
#pragma unroll
  for (int i2 = 0; i2 < 2; ++i2)
    kr[i2] = *(const short8*)(Kg + (size_t)(krow + i2 * 32) * CK + kcol);
#pragma unroll
  for (int i2 = 0; i2 < 2; ++i2)
    vr[i2] = *(const short8*)(Vg + (size_t)vrow * HW + vcol + i2 * 8);

  // prologue: tile 0 into buffer 0
#pragma unroll
  for (int i2 = 0; i2 < 2; ++i2)
    *(short8*)&Kl[0][kslot[i2] * 136 + kcol] = kr[i2];
#pragma unroll
  for (int i2 = 0; i2 < 2; ++i2)
    *(short8*)&Vl[0][vrow * 72 + vcol + i2 * 8] = vr[i2];
  __syncthreads();

  for (int it = 0; it < ITERS; ++it) {
    const int cur = it & 1;
    const unsigned short* Klc = &Kl[cur][0];
    const unsigned short* Vlc = &Vl[cur][0];

    if (it + 1 < ITERS) {  // issue prefetch of tile t+1 (lands during compute)
      const unsigned short* Kn = Kg + (size_t)((it + 1) * 64) * CK;
      const unsigned short* Vn = Vg + (it + 1) * 64;
#pragma unroll
      for (int i2 = 0; i2 < 2; ++i2)
        kr[i2] = *(const short8*)(Kn + (size_t)(krow + i2 * 32) * CK + kcol);
#pragma unroll
      for (int i2 = 0; i2 < 2; ++i2)
        vr[i2] = *(const short8*)(Vn + (size_t)vrow * HW + vcol + i2 * 8);
    }

    __builtin_amdgcn_s_setprio(1);
    // Per 32-wide PV k-chunk: QK^T on tile pair (2kp, 2kp+1) -> exp2 ->
    // fp32 L accumulate + pack -> PV straight from the packed A-frag.
#pragma unroll
    for (int kp = 0; kp < 2; ++kp) {
      floatx4 sA0 = (floatx4){0.f, 0.f, 0.f, 0.f};
      floatx4 sA1 = (floatx4){0.f, 0.f, 0.f, 0.f};
      floatx4 sB0 = (floatx4){0.f, 0.f, 0.f, 0.f};
      floatx4 sB1 = (floatx4){0.f, 0.f, 0.f, 0.f};
#pragma unroll
      for (int ks = 0; ks < 4; ++ks) {
        const short8 kfA = *(const short8*)&Klc[((2 * kp) * 16 + lane16) * 136 + ks * 32 + quad * 8];
        const short8 kfB = *(const short8*)&Klc[((2 * kp + 1) * 16 + lane16) * 136 + ks * 32 + quad * 8];
        sA0 = MFMA(kfA, qf[0][ks], sA0);
        sA1 = MFMA(kfA, qf[1][ks], sA1);
        sB0 = MFMA(kfB, qf[0][ks], sB0);
        sB1 = MFMA(kfB, qf[1][ks], sB1);
      }
      const float eA00 = __builtin_amdgcn_exp2f(sA0[0]), eA01 = __builtin_amdgcn_exp2f(sA0[1]);
      const float eA02 = __builtin_amdgcn_exp2f(sA0[2]), eA03 = __builtin_amdgcn_exp2f(sA0[3]);
      const float eB00 = __builtin_amdgcn_exp2f(sB0[0]), eB01 = __builtin_amdgcn_exp2f(sB0[1]);
      const float eB02 = __builtin_amdgcn_exp2f(sB0[2]), eB03 = __builtin_amdgcn_exp2f(sB0[3]);
      const float eA10 = __builtin_amdgcn_exp2f(sA1[0]), eA11 = __builtin_amdgcn_exp2f(sA1[1]);
      const float eA12 = __builtin_amdgcn_exp2f(sA1[2]), eA13 = __builtin_amdgcn_exp2f(sA1[3]);
      const float eB10 = __builtin_amdgcn_exp2f(sB1[0]), eB11 = __builtin_amdgcn_exp2f(sB1[1]);
      const float eB12 = __builtin_amdgcn_exp2f(sB1[2]), eB13 = __builtin_amdgcn_exp2f(sB1[3]);

      lsum0 += ((eA00 + eA01) + (eA02 + eA03)) + ((eB00 + eB01) + (eB02 + eB03));
      lsum1 += ((eA10 + eA11) + (eA12 + eA13)) + ((eB10 + eB11) + (eB12 + eB13));

      union { unsigned u[4]; short8 s; } pf0, pf1;
      pf0.u[0] = pack2(eA00, eA01);
      pf0.u[1] = pack2(eA02, eA03);
      pf0.u[2] = pack2(eB00, eB01);
      pf0.u[3] = pack2(eB02, eB03);
      pf1.u[0] = pack2(eA10, eA11);
      pf1.u[1] = pack2(eA12, eA13);
      pf1.u[2] = pack2(eB10, eB11);
      pf1.u[3] = pack2(eB12, eB13);

#pragma unroll
      for (int nf = 0; nf < 8; ++nf) {
        const short8 vf = *(const short8*)&Vlc[(nf * 16 + lane16) * 72 + kp * 32 + quad * 8];
        O[0][nf] = MFMA(pf0.s, vf, O[0][nf]);
        O[1][nf] = MFMA(pf1.s, vf, O[1][nf]);
      }
    }
    __builtin_amdgcn_s_setprio(0);

    if (it + 1 < ITERS) {  // write-late: stage tile t+1 into the other buffer
      const int nxt = cur ^ 1;
#pragma unroll
      for (int i2 = 0; i2 < 2; ++i2)
        *(short8*)&Kl[nxt][kslot[i2] * 136 + kcol] = kr[i2];
#pragma unroll
      for (int i2 = 0; i2 < 2; ++i2)
        *(short8*)&Vl[nxt][vrow * 72 + vcol + i2 * 8] = vr[i2];
    }
    __syncthreads();
  }

  // epilogue: bf16 unnormalized partial O + fp32 l. Waves 0-3 -> even
  // 128-row chunk (qt*2), waves 4-7 -> odd chunk (qt*2+1); row uses wave&3.
  const int qt128 = qt * 2 + (wave >> 2);
  const int w4 = wave & 3;
  const int chunk = (b * 32 + qt128) * NKC + kc;
  unsigned short* Op = OpartH + (size_t)chunk * (128 * 128);
#pragma unroll
  for (int mt = 0; mt < 2; ++mt)
#pragma unroll
    for (int nf = 0; nf < 8; ++nf)
#pragma unroll
      for (int r = 0; r < 4; ++r)
        Op[(size_t)(w4 * 32 + mt * 16 + quad * 4 + r) * 128 + nf * 16 + lane16] =
            f2bf(O[mt][nf][r]);

  // reduce the row sums across the 4 quads (lanes l16 + {0,16,32,48})
  lsum0 += __shfl_xor(lsum0, 16);
  lsum0 += __shfl_xor(lsum0, 32);
  lsum1 += __shfl_xor(lsum1, 16);
  lsum1 += __shfl_xor(lsum1, 32);
  if (quad == 0) {
    float* Mp = Ml + (size_t)chunk * 128 + w4 * 32;
    Mp[lane16]      = lsum0;   // q = l16
    Mp[16 + lane16] = lsum1;   // q = l16 + 16
  }
}

// ---------------------------------------------------------------------------
// Kernel 3: fused combine + out-projection (bf16 partials, packed WoP).
// grid (256 p-tiles of 16, 4 batch), block 256. (round-11 exact)
// ---------------------------------------------------------------------------
template<int NKC>
__global__ __launch_bounds__(256) void outproj_kernel(
    const unsigned short* __restrict__ OpartH, const float* __restrict__ Ml,
    const unsigned short* __restrict__ WoP, const float* __restrict__ bo,
    float* __restrict__ out)
{
  const int tid = threadIdx.x;
  const int pt = blockIdx.x;
  const int b  = blockIdx.y;
  const int qt = pt >> 3;
  const int q0 = (pt & 7) * 16;
  const int chunk0 = (b * 32 + qt) * NKC;

  __shared__ unsigned short Ctile[16 * 136];

  {
    const int row = tid >> 4;
    const int c8  = (tid & 15) * 8;
    float L = 0.f;
#pragma unroll
    for (int k = 0; k < NKC; ++k) L += Ml[(size_t)(chunk0 + k) * 128 + q0 + row];
    float acc[8];
#pragma unroll
    for (int i = 0; i < 8; ++i) acc[i] = 0.f;
#pragma unroll
    for (int k = 0; k < NKC; ++k) {
      const short8 v = *(const short8*)(OpartH + (size_t)(chunk0 + k) * 16384 +
                                        (size_t)(q0 + row) * 128 + c8);
#pragma unroll
      for (int i = 0; i < 8; ++i) acc[i] += bf2f((unsigned short)v[i]);
    }
    const float inv = 1.f / L;
#pragma unroll
    for (int i = 0; i < 8; ++i) acc[i] *= inv;
    *(short8*)&Ctile[row * 136 + c8] = pack8(acc);
  }
  __syncthreads();

  const int wave = tid >> 6;
  const int lane = tid & 63;
  const int lane16 = lane & 15;
  const int quad = lane >> 4;

  floatx4 acc[4];
#pragma unroll
  for (int mt = 0; mt < 4; ++mt) acc[mt] = (floatx4){0.f, 0.f, 0.f, 0.f};

#pragma unroll
  for (int ks = 0; ks < 4; ++ks) {
    const short8 bf = *(const short8*)&Ctile[lane16 * 136 + ks * 32 + quad * 8];
#pragma unroll
    for (int mt = 0; mt < 4; ++mt) {
      const short8 af = *(const short8*)&WoP[(size_t)((((ks * 4 + wave) * 4 + mt) * 64) + lane) * 8];
      acc[mt] = MFMA(af, bf, acc[mt]);
    }
  }

#pragma unroll
  for (int mt = 0; mt < 4; ++mt) {
#pragma unroll
    for (int r = 0; r < 4; ++r) {
      const int o = wave * 64 + mt * 16 + quad * 4 + r;
      float* dst = out + ((size_t)b * COUT + o) * HW + qt * 128 + q0;
      dst[lane16] = acc[mt][r] + bo[o];
    }
  }
}

extern "C" void kernel_launch(void* const* d_in, const int* in_sizes, int n_in,
                              void* d_out, int out_size, void* d_ws, size_t ws_size,
                              hipStream_t stream)
{
  (void)in_sizes; (void)n_in; (void)out_size;
  const float* x_enc = (const float*)d_in[0];
  const float* x_dec = (const float*)d_in[1];
  const float* wk    = (const float*)d_in[2];
  const float* bk    = (const float*)d_in[3];
  const float* gk    = (const float*)d_in[4];
  const float* betak = (const float*)d_in[5];
  const float* mk    = (const float*)d_in[6];
  const float* vk    = (const float*)d_in[7];
  const float* wq    = (const float*)d_in[8];
  const float* bq    = (const float*)d_in[9];
  const float* gq    = (const float*)d_in[10];
  const float* betaq = (const float*)d_in[11];
  const float* mq    = (const float*)d_in[12];
  const float* vq    = (const float*)d_in[13];
  const float* wv    = (const float*)d_in[14];
  const float* bv    = (const float*)d_in[15];
  const float* wo    = (const float*)d_in[16];
  const float* bo    = (const float*)d_in[17];
  float* out = (float*)d_out;

  const size_t qkv = (size_t)NB * HW * CK;  // elems per bf16 tensor
  unsigned short* WqP  = (unsigned short*)d_ws;      // 32768 shorts
  unsigned short* WkvP = WqP + 32768;                // 65536 shorts
  unsigned short* WoP  = WkvP + 65536;               // 32768 shorts
  unsigned short* Qb   = WoP + 32768;
  unsigned short* Kb   = Qb + qkv;
  unsigned short* Vt   = Kb + qkv;
  unsigned short* OpartH = Vt + qkv;                 // bf16 partials
  const size_t fixed_bytes = 131072 * 2 + 3 * qkv * 2;

  prep_kernel<<<dim3(64), 256, 0, stream>>>(wq, wk, wv, wo, WqP, WkvP, WoP);
  proj_kernel<<<dim3(64, 4, 2), 256, 0, stream>>>(
      x_enc, x_dec, WqP, WkvP,
      bq, gq, betaq, mq, vq, bk, gk, betak, mk, vk, bv, Qb, Kb, Vt);

  auto need = [&](int nkc) {
    return fixed_bytes + (size_t)128 * nkc * 16384 * 2      // OpartH bf16
                       + (size_t)128 * nkc * 128 * 4;       // Ml fp32
  };
  if (ws_size >= need(8)) {
    float* Ml = (float*)(OpartH + (size_t)128 * 8 * 16384);
    attn_kernel8<8><<<dim3(512), 512, 0, stream>>>(Qb, Kb, Vt, OpartH, Ml);
    outproj_kernel<8><<<dim3(256, 4), 256, 0, stream>>>(OpartH, Ml, WoP, bo, out);
  } else if (ws_size >= need(4)) {
    float* Ml = (float*)(OpartH + (size_t)128 * 4 * 16384);
    attn_kernel8<4><<<dim3(256), 512, 0, stream>>>(Qb, Kb, Vt, OpartH, Ml);
    outproj_kernel<4><<<dim3(256, 4), 256, 0, stream>>>(OpartH, Ml, WoP, bo, out);
  } else if (ws_size >= need(2)) {
    float* Ml = (float*)(OpartH + (size_t)128 * 2 * 16384);
    attn_kernel8<2><<<dim3(128), 512, 0, stream>>>(Qb, Kb, Vt, OpartH, Ml);
    outproj_kernel<2><<<dim3(256, 4), 256, 0, stream>>>(OpartH, Ml, WoP, bo, out);
  } else {
    float* Ml = (float*)(OpartH + (size_t)128 * 1 * 16384);
    attn_kernel8<1><<<dim3(64), 512, 0, stream>>>(Qb, Kb, Vt, OpartH, Ml);
    outproj_kernel<1><<<dim3(256, 4), 256, 0, stream>>>(OpartH, Ml, WoP, bo, out);
  }
}